// Round 3
// baseline (979.682 us; speedup 1.0000x reference)
//
#include <hip/hip_runtime.h>
#include <hip/hip_bf16.h>
#include <math.h>

typedef __hip_bfloat16 bf16;

#define NRES 256
#define LC   32
#define HCH  128
#define ECH  64
#define NH   4
#define NCA  14
#define KNNK 8
#define DH   32
#define NKE  (NRES*KNNK)      // 2048
#define NEDGE (NKE+NRES)      // 2304
#define NE1  64

// ---- fp32 converted-input region offsets (floats) ----
#define O_RESH   0
#define O_RESX   458752
#define O_LPOS   469504
#define O_LFEAT  469888
#define O_LMASK  486272
#define O_LNG    486400
#define O_LNB    486528
#define O_LN1G   486656
#define O_LN1B   486784
#define O_WQ     486912
#define O_WK     503296
#define O_WV     519680
#define O_WKL    536064
#define O_WVL    552448
#define O_WO     568832
#define O_WOL    585216
#define O_WOL1   601600
#define O_TIW1   617984
#define O_TIB1   658944
#define O_TIW2   659072
#define O_TIB2   659200
#define O_SDW1   659204
#define O_SDB1   667396
#define O_SDW2   667524
#define O_SDB2   668036
#define O_SD1W1  668040
#define O_SD1B1  676232
#define O_SD1W2  676360
#define O_SD1B2  676872
#define TOTCVT   676876
#define CVT_RSV  676880

#define OUTX_OFF 458752
#define OUTL_OFF 469504

__constant__ int c_counts[21] = {14,5,11,8,8,6,9,9,4,10,8,8,9,8,11,7,6,7,14,12,7};

__device__ __forceinline__ float b2f(bf16 x){ return __bfloat162float(x); }
__device__ __forceinline__ float sspf(float x){
  return fmaxf(x,0.f) + log1pf(expf(-fabsf(x))) - 0.6931471805599453f;
}
__device__ __forceinline__ float bflo(unsigned u){ return __uint_as_float(u<<16); }
__device__ __forceinline__ float bfhi(unsigned u){ return __uint_as_float(u & 0xffff0000u); }
__device__ __forceinline__ int ccount(int s){ return c_counts[s<0?0:(s>20?20:s)]; }
__device__ __forceinline__ void storeOut(void* out, int isbf, int idx, float v){
  if (isbf) ((bf16*)out)[idx] = __float2bfloat16(v);
  else      ((float*)out)[idx] = v;
}

// ---------------------------------------------------------------- kdet: detect input float dtype
// bf16 data: low 16 bits of each 32b word are a bf16 value ~N(0,1) -> exponent near 127.
// fp32 data: low 16 bits are low mantissa bits -> uniform -> exponent rarely near 127.
__global__ __launch_bounds__(64) void kdet(const unsigned* __restrict__ resH_raw, int* __restrict__ flag)
{
  int tid = threadIdx.x;
  unsigned w = resH_raw[tid];
  unsigned lo = w & 0xFFFFu;
  int e = (lo >> 7) & 0xFF;
  int good = (lo == 0u) || (e >= 121 && e <= 133);
  unsigned long long m = __ballot(good);
  if (tid == 0) flag[0] = (__popcll(m) >= 40) ? 1 : 0;   // 1 = inputs are bf16
}

// ---------------------------------------------------------------- kcvt: all float inputs -> fp32 copies
__global__ __launch_bounds__(256) void kcvt(
    const int* __restrict__ flag,
    const void* s0,const void* s1,const void* s2,const void* s3,const void* s4,
    const void* s5,const void* s6,const void* s7,const void* s8,const void* s9,
    const void* s10,const void* s11,const void* s12,const void* s13,const void* s14,
    const void* s15,const void* s16,const void* s17,const void* s18,const void* s19,
    const void* s20,const void* s21,const void* s22,const void* s23,const void* s24,
    const void* s25,const void* s26,const void* s27,const void* s28,
    float* __restrict__ dst)
{
  int g = blockIdx.x*256 + threadIdx.x;
  if (g >= TOTCVT) return;
  const void* src; int l;
  if      (g < O_RESX ) { src=s0;  l=g; }
  else if (g < O_LPOS ) { src=s1;  l=g-O_RESX; }
  else if (g < O_LFEAT) { src=s2;  l=g-O_LPOS; }
  else if (g < O_LMASK) { src=s3;  l=g-O_LFEAT; }
  else if (g < O_LNG  ) { src=s4;  l=g-O_LMASK; }
  else if (g < O_LNB  ) { src=s5;  l=g-O_LNG; }
  else if (g < O_LN1G ) { src=s6;  l=g-O_LNB; }
  else if (g < O_LN1B ) { src=s7;  l=g-O_LN1G; }
  else if (g < O_WQ   ) { src=s8;  l=g-O_LN1B; }
  else if (g < O_WK   ) { src=s9;  l=g-O_WQ; }
  else if (g < O_WV   ) { src=s10; l=g-O_WK; }
  else if (g < O_WKL  ) { src=s11; l=g-O_WV; }
  else if (g < O_WVL  ) { src=s12; l=g-O_WKL; }
  else if (g < O_WO   ) { src=s13; l=g-O_WVL; }
  else if (g < O_WOL  ) { src=s14; l=g-O_WO; }
  else if (g < O_WOL1 ) { src=s15; l=g-O_WOL; }
  else if (g < O_TIW1 ) { src=s16; l=g-O_WOL1; }
  else if (g < O_TIB1 ) { src=s17; l=g-O_TIW1; }
  else if (g < O_TIW2 ) { src=s18; l=g-O_TIB1; }
  else if (g < O_TIB2 ) { src=s19; l=g-O_TIW2; }
  else if (g < O_SDW1 ) { src=s20; l=0; }             // Ti_b2 scalar, padded region
  else if (g < O_SDB1 ) { src=s21; l=g-O_SDW1; }
  else if (g < O_SDW2 ) { src=s22; l=g-O_SDB1; }
  else if (g < O_SDB2 ) { src=s23; l=g-O_SDW2; }
  else if (g < O_SD1W1) { src=s24; l=g-O_SDB2; }
  else if (g < O_SD1B1) { src=s25; l=g-O_SD1W1; }
  else if (g < O_SD1W2) { src=s26; l=g-O_SD1B1; }
  else if (g < O_SD1B2) { src=s27; l=g-O_SD1W2; }
  else                  { src=s28; l=g-O_SD1B2; }
  float v = (*flag) ? b2f(((const bf16*)src)[l]) : ((const float*)src)[l];
  dst[g] = v;
}

// ---------------------------------------------------------------- k0: transpose weights + inv_row
// wt slots: 0 WQ,1 WK,2 WV,3 WO,4 WKl,5 WVl,6 WOl,7 WOl1,8 TiQ,9 TiK  -- wt[m][c][o] = W[o][c]
__global__ __launch_bounds__(256) void k0_prep(
    const float* __restrict__ cvt, const int* __restrict__ row1,
    float* __restrict__ wt, int* __restrict__ inv_row)
{
  int bid = blockIdx.x, tid = threadIdx.x;
  if (bid == 640){
    if (tid < NRES) inv_row[tid] = -1;
    __syncthreads();
    if (tid < NE1) inv_row[row1[tid] & 255] = tid;
    return;
  }
  int gid = bid*256 + tid;
  int m = gid >> 14;
  int j = gid & 16383;
  int o = j >> 7, c = j & 127;
  float v;
  switch(m){
    case 0: v = cvt[O_WQ  + j]; break;
    case 1: v = cvt[O_WK  + j]; break;
    case 2: v = cvt[O_WV  + j]; break;
    case 3: v = cvt[O_WO  + j]; break;
    case 4: v = cvt[O_WKL + j]; break;
    case 5: v = cvt[O_WVL + j]; break;
    case 6: v = cvt[O_WOL + j]; break;
    case 7: v = cvt[O_WOL1+ j]; break;
    case 8: v = cvt[O_TIW1 + o*320 + c]; break;        // Ti_w1[:, :128]
    default:v = cvt[O_TIW1 + o*320 + 128 + c]; break;  // Ti_w1[:, 128:256]
  }
  wt[m*16384 + c*128 + o] = v;
}

// ------------------------------------------------- k1: residue LN + 5 projections
__global__ __launch_bounds__(128) void k1_res_proj(
    const float* __restrict__ cvt, const float* __restrict__ wt, float* __restrict__ resHn,
    float* __restrict__ Qw, float* __restrict__ Kw, float* __restrict__ Vw,
    float* __restrict__ TQw, float* __restrict__ TKw)
{
  int n = blockIdx.x, tid = threadIdx.x;
  __shared__ float xr[NCA][HCH];
  __shared__ float qr[NCA][HCH];
  __shared__ float kr[NCA][HCH];
  __shared__ float sred[2];
  float g = cvt[O_LNG+tid], bb = cvt[O_LNB+tid];
  for (int p=0;p<NCA;p++){
    float v = cvt[O_RESH + (n*NCA+p)*HCH + tid];
    float s = v;
    for (int off=1; off<64; off<<=1) s += __shfl_xor(s, off);
    if ((tid&63)==0) sred[tid>>6] = s;
    __syncthreads();
    float mu = (sred[0]+sred[1])*(1.f/HCH);
    __syncthreads();
    float d = v-mu;
    s = d*d;
    for (int off=1; off<64; off<<=1) s += __shfl_xor(s, off);
    if ((tid&63)==0) sred[tid>>6] = s;
    __syncthreads();
    float var = (sred[0]+sred[1])*(1.f/HCH);
    __syncthreads();
    float xh = d*rsqrtf(var+1e-5f)*g + bb;
    xr[p][tid] = xh;
    resHn[(n*NCA+p)*HCH + tid] = xh;
  }
  __syncthreads();
  const float* WQt = wt;
  const float* WKt = wt + 16384;
  const float* WVt = wt + 2*16384;
  const float* TQt = wt + 8*16384;
  const float* TKt = wt + 9*16384;
  {
    float aQ[NCA], aK[NCA], aV[NCA];
    #pragma unroll
    for (int p=0;p<NCA;p++){ aQ[p]=0.f; aK[p]=0.f; aV[p]=0.f; }
    for (int c=0;c<HCH;c++){
      float wq = WQt[c*128+tid], wk = WKt[c*128+tid], wv = WVt[c*128+tid];
      #pragma unroll
      for (int p=0;p<NCA;p++){
        float x = xr[p][c];
        aQ[p] += x*wq; aK[p] += x*wk; aV[p] += x*wv;
      }
    }
    for (int p=0;p<NCA;p++){
      qr[p][tid] = aQ[p]; kr[p][tid] = aK[p];
      Qw[(n*NCA+p)*HCH+tid] = aQ[p];
      Kw[(n*NCA+p)*HCH+tid] = aK[p];
      Vw[(n*NCA+p)*HCH+tid] = aV[p];
    }
  }
  __syncthreads();
  {
    float aTQ[NCA], aTK[NCA];
    #pragma unroll
    for (int p=0;p<NCA;p++){ aTQ[p]=0.f; aTK[p]=0.f; }
    for (int c=0;c<HCH;c++){
      float wtq = TQt[c*128+tid], wtk = TKt[c*128+tid];
      #pragma unroll
      for (int p=0;p<NCA;p++){
        aTQ[p] += qr[p][c]*wtq; aTK[p] += kr[p][c]*wtk;
      }
    }
    for (int p=0;p<NCA;p++){
      TQw[(n*NCA+p)*HCH+tid] = aTQ[p];
      TKw[(n*NCA+p)*HCH+tid] = aTK[p];
    }
  }
}

// ------------------------------------------------- k2: KNN (replicates lax.top_k tie-break)
__global__ __launch_bounds__(256) void k2_knn(
    const float* __restrict__ cvt, const int* __restrict__ batch, int* __restrict__ nbr)
{
  int n = blockIdx.x, j = threadIdx.x;
  __shared__ float sd[256];
  __shared__ float rd[256];
  __shared__ int   ri[256];
  float cx = cvt[O_RESX+(n*NCA+1)*3+0];
  float cy = cvt[O_RESX+(n*NCA+1)*3+1];
  float cz = cvt[O_RESX+(n*NCA+1)*3+2];
  float jx = cvt[O_RESX+(j*NCA+1)*3+0];
  float jy = cvt[O_RESX+(j*NCA+1)*3+1];
  float jz = cvt[O_RESX+(j*NCA+1)*3+2];
  float dx=cx-jx, dy=cy-jy, dz=cz-jz;
  float d2 = dx*dx+dy*dy+dz*dz;
  bool bad = (batch[j]!=batch[n]) || (j==n);
  sd[j] = bad ? INFINITY : d2;
  __syncthreads();
  for (int k=0;k<KNNK;k++){
    rd[j]=sd[j]; ri[j]=j;
    __syncthreads();
    for (int off=128; off>0; off>>=1){
      if (j<off){
        float da=rd[j], db=rd[j+off];
        int ia=ri[j], ib=ri[j+off];
        if (db<da || (db==da && ib<ia)){ rd[j]=db; ri[j]=ib; }
      }
      __syncthreads();
    }
    if (j==0){ nbr[n*KNNK+k]=ri[0]; sd[ri[0]] = INFINITY; }
    __syncthreads();
  }
}

// ------------------------------------------------- k5: ligand LN + Kl/Vl projections
__global__ __launch_bounds__(128) void k5_ligproj(
    const float* __restrict__ cvt, const float* __restrict__ wt, float* __restrict__ lf,
    float* __restrict__ Klw, float* __restrict__ Vlw)
{
  int rb = blockIdx.x, tid = threadIdx.x;
  __shared__ float x[HCH];
  __shared__ float sred[2];
  float v = cvt[O_LFEAT + rb*HCH + tid];
  float s=v;
  for (int off=1; off<64; off<<=1) s += __shfl_xor(s, off);
  if ((tid&63)==0) sred[tid>>6]=s;
  __syncthreads();
  float mu=(sred[0]+sred[1])*(1.f/HCH);
  __syncthreads();
  float d=v-mu; s=d*d;
  for (int off=1; off<64; off<<=1) s += __shfl_xor(s, off);
  if ((tid&63)==0) sred[tid>>6]=s;
  __syncthreads();
  float var=(sred[0]+sred[1])*(1.f/HCH);
  float xh = d*rsqrtf(var+1e-5f)*cvt[O_LN1G+tid] + cvt[O_LN1B+tid];
  x[tid]=xh; lf[rb*HCH+tid]=xh;
  __syncthreads();
  const float* WKlt = wt + 4*16384;
  const float* WVlt = wt + 5*16384;
  float aK=0.f, aV=0.f;
  for (int c=0;c<HCH;c++){
    float xc=x[c];
    aK += xc*WKlt[c*128+tid];
    aV += xc*WVlt[c*128+tid];
  }
  Klw[rb*HCH+tid]=aK; Vlw[rb*HCH+tid]=aV;
}

// ------------------------------------------------- k3a: residue-edge logits + Ti MLP
__global__ __launch_bounds__(256) void k3a_logits(
    const float* __restrict__ cvt, const int* __restrict__ nbr,
    const float* __restrict__ Qw, const float* __restrict__ Kw,
    const float* __restrict__ TQw, const float* __restrict__ TKw,
    float* __restrict__ LGw, float* __restrict__ FRw)
{
  __shared__ __align__(16) bf16 w1s[8192];   // sD_w1 (bf16-rounded; exact if inputs were bf16)
  __shared__ __align__(16) bf16 w3s[8192];   // Ti_w1[:,256:]
  __shared__ float b1s[128], b3s[128], w2s[512], tw2[128], sb2[4], tb2[1];
  __shared__ float Xr[42], Xc[42];
  int e = blockIdx.x, tid = threadIdx.x;
  int rr, cc;
  if (e < NKE){ rr = e >> 3; cc = nbr[e] & 255; } else { rr = e - NKE; cc = rr; }

  for (int i=tid;i<8192;i+=256) w1s[i] = __float2bfloat16(cvt[O_SDW1+i]);
  for (int i=tid;i<8192;i+=256){ int o=i>>6, c=i&63; w3s[i] = __float2bfloat16(cvt[O_TIW1 + o*320 + 256 + c]); }
  if (tid < 128){ b1s[tid]=cvt[O_SDB1+tid]; b3s[tid]=cvt[O_TIB1+tid]; tw2[tid]=cvt[O_TIW2+tid]; }
  for (int i=tid;i<512;i+=256) w2s[i]=cvt[O_SDW2+i];
  if (tid < 4) sb2[tid]=cvt[O_SDB2+tid];
  if (tid == 4) tb2[0]=cvt[O_TIB2];
  if (tid >= 64 && tid < 64+42){
    int i=tid-64; int p=i/3, jx=i%3;
    Xr[i] = cvt[O_RESX+(rr*NCA+p)*3+jx];
    Xc[i] = cvt[O_RESX+(cc*NCA+p)*3+jx];
  }
  __syncthreads();

  if (tid < 196){
    int p = tid/14, q = tid%14;
    float dx=Xr[p*3]-Xc[q*3], dy=Xr[p*3+1]-Xc[q*3+1], dz=Xr[p*3+2]-Xc[q*3+2];
    float d = sqrtf(fmaxf(dx*dx+dy*dy+dz*dz, 1e-12f));
    const float step = 10.0f/63.0f;
    const float coef = -0.5f/(step*step);
    float dr[ECH];
    #pragma unroll
    for (int c=0;c<ECH;c++){ float t = d - step*(float)c; dr[c] = expf(coef*t*t); }

    // MLP1: relu(drep@sD_w1.T + b1) @ sD_w2.T + b2
    float sg0=sb2[0], sg1=sb2[1], sg2=sb2[2], sg3=sb2[3];
    for (int o=0;o<HCH;o++){
      float a1 = b1s[o];
      const unsigned* wa = ((const unsigned*)w1s) + o*32;
      #pragma unroll
      for (int c2=0;c2<32;c2++){
        unsigned u = wa[c2];
        a1 += dr[2*c2]*bflo(u) + dr[2*c2+1]*bfhi(u);
      }
      a1 = fmaxf(a1, 0.f);
      sg0 += a1*w2s[o]; sg1 += a1*w2s[128+o]; sg2 += a1*w2s[256+o]; sg3 += a1*w2s[384+o];
    }

    // MLP2 (Ti): relu(TQ[p]+TK[q]+drep@w3+b3) @ tw2 + tb2
    const float* TQp = TQw + (rr*NCA+p)*HCH;
    const float* TKp = TKw + (cc*NCA+q)*HCH;
    float fa = tb2[0];
    for (int o=0;o<HCH;o++){
      float a2 = b3s[o] + TQp[o] + TKp[o];
      const unsigned* wb = ((const unsigned*)w3s) + o*32;
      #pragma unroll
      for (int c2=0;c2<32;c2++){
        unsigned u = wb[c2];
        a2 += dr[2*c2]*bflo(u) + dr[2*c2+1]*bfhi(u);
      }
      fa += fmaxf(a2,0.f)*tw2[o];
    }

    // QK^T per head
    const float* Qp = Qw + (rr*NCA+p)*HCH;
    const float* Kp = Kw + (cc*NCA+q)*HCH;
    float qk0=0,qk1=0,qk2=0,qk3=0;
    #pragma unroll
    for (int dd=0;dd<DH;dd++){
      qk0 += Qp[dd]   *Kp[dd];
      qk1 += Qp[32+dd]*Kp[32+dd];
      qk2 += Qp[64+dd]*Kp[64+dd];
      qk3 += Qp[96+dd]*Kp[96+dd];
    }
    const float isq = 0.17677669529663687f;   // 1/sqrt(32)
    LGw[e*784 + 0*196 + tid] = qk0*isq + sg0;
    LGw[e*784 + 1*196 + tid] = qk1*isq + sg1;
    LGw[e*784 + 2*196 + tid] = qk2*isq + sg2;
    LGw[e*784 + 3*196 + tid] = qk3*isq + sg3;
    FRw[e*196 + tid] = fa;
  }
}

// ------------------------------------------------- k3b: residue-edge softmax / r / aV / dX
__global__ __launch_bounds__(256) void k3b_att(
    const float* __restrict__ cvt, const int* __restrict__ res_S, const int* __restrict__ nbr,
    const float* __restrict__ LGw, const float* __restrict__ FRw, const float* __restrict__ Vw,
    float* __restrict__ r_ws, float* __restrict__ aVe, float* __restrict__ dXe)
{
  __shared__ float LG[784];
  __shared__ float FR[196];
  __shared__ float Vc[1848];   // V[col], stride 132
  __shared__ float Xr[42], Xc[42], amr[14], amc[14], rpart[56], cnts[2];
  int e = blockIdx.x, tid = threadIdx.x;
  int rr, cc;
  if (e < NKE){ rr = e >> 3; cc = nbr[e] & 255; } else { rr = e - NKE; cc = rr; }

  for (int i=tid;i<784;i+=256) LG[i] = LGw[e*784+i];
  if (tid < 196) FR[tid] = FRw[e*196+tid];
  for (int i=tid;i<NCA*HCH;i+=256){
    int p=i>>7, c=i&127;
    Vc[p*132+c] = Vw[cc*NCA*HCH + i];
  }
  if (tid >= 196 && tid < 196+42){
    int i=tid-196; int p=i/3, jx=i%3;
    Xr[i] = cvt[O_RESX+(rr*NCA+p)*3+jx];
    Xc[i] = cvt[O_RESX+(cc*NCA+p)*3+jx];
  }
  if (tid >= 242 && tid < 242+NCA){       // 242+14 = 256: all lanes exist
    int p=tid-242;
    amr[p] = (p < ccount(res_S[rr])) ? 1.f : 0.f;
    amc[p] = (p < ccount(res_S[cc])) ? 1.f : 0.f;
  }
  __syncthreads();

  if (tid < 56){
    int h=tid/14, pp=tid%14;
    float ap = amr[pp];
    float row[NCA];
    float s=0;
    #pragma unroll
    for (int qq=0;qq<NCA;qq++){ row[qq]=LG[h*196+pp*14+qq]; s += row[qq]*amc[qq]; }
    rpart[h*14+pp] = s*ap;
    float m=-INFINITY;
    #pragma unroll
    for (int qq=0;qq<NCA;qq++) m=fmaxf(m,row[qq]);
    float sum=0;
    #pragma unroll
    for (int qq=0;qq<NCA;qq++){ row[qq]=expf(row[qq]-m); sum+=row[qq]; }
    float inv=1.f/sum, s2=0;
    #pragma unroll
    for (int qq=0;qq<NCA;qq++){ row[qq]=row[qq]*inv*ap*amc[qq]; s2+=row[qq]; }
    float inv2=1.f/(s2+1e-7f);
    #pragma unroll
    for (int qq=0;qq<NCA;qq++) LG[h*196+pp*14+qq]=row[qq]*inv2;
  }
  if (tid == 56){
    float sr=0, sc=0;
    for (int i=0;i<NCA;i++){ sr+=amr[i]; sc+=amc[i]; }
    cnts[0]=sr; cnts[1]=sc;
  }
  __syncthreads();
  if (tid < NH){
    float s=0;
    for (int pp=0;pp<NCA;pp++) s += rpart[tid*14+pp];
    r_ws[e*NH+tid] = s/(cnts[0]*cnts[1]);
  }
  if (tid < 196){
    int p=tid/14, q=tid%14;
    float ma = 0.25f*(LG[p*14+q] + LG[196+p*14+q] + LG[392+p*14+q] + LG[588+p*14+q]);
    FR[tid] *= ma;
  }
  __syncthreads();
  if (tid < NCA){
    int pp=tid;
    float ax=0, ay=0, az=0;
    #pragma unroll
    for (int qq=0;qq<NCA;qq++){
      float dx=Xr[pp*3]-Xc[qq*3], dy=Xr[pp*3+1]-Xc[qq*3+1], dz=Xr[pp*3+2]-Xc[qq*3+2];
      float nrm = sqrtf(fmaxf(dx*dx+dy*dy+dz*dz,1e-12f));
      float sc = FR[pp*14+qq]/(nrm+1e-5f);
      ax += sc*dx; ay += sc*dy; az += sc*dz;
    }
    dXe[(e*NCA+pp)*3+0]=ax; dXe[(e*NCA+pp)*3+1]=ay; dXe[(e*NCA+pp)*3+2]=az;
  }
  #pragma unroll
  for (int rep=0;rep<7;rep++){
    int jdx = rep*256 + tid;
    int h = jdx/448, rem = jdx%448;
    int pp = rem>>5, dd = rem&31;
    float acc=0;
    #pragma unroll
    for (int qq=0;qq<NCA;qq++) acc += LG[h*196+pp*14+qq]*Vc[qq*132 + h*32 + dd];
    aVe[e*1792 + jdx] = acc;
  }
}

// ------------------------------------------------- k4: per-residue beta + updH + WO + dX
__global__ __launch_bounds__(128) void k4_agg(
    const float* __restrict__ cvt, const int* __restrict__ res_S, const int* __restrict__ inv_row,
    const float* __restrict__ r_ws, const float* __restrict__ aVe, const float* __restrict__ dXe,
    const float* __restrict__ resHn, const float* __restrict__ wt, const int* __restrict__ flag,
    float* __restrict__ resH2, float* __restrict__ resX2, void* __restrict__ d_out)
{
  int n = blockIdx.x, tid = threadIdx.x;
  __shared__ float beta[9][NH];
  __shared__ float betam[9];
  __shared__ float Xs[NCA][HCH];
  if (tid < NH){
    int h = tid;
    float rv[9], m=-INFINITY;
    #pragma unroll
    for (int k=0;k<9;k++){
      int ek = (k<KNNK)? n*KNNK+k : NKE+n;
      rv[k] = r_ws[ek*NH+h];
      m = fmaxf(m, rv[k]);
    }
    float s=0;
    #pragma unroll
    for (int k=0;k<9;k++){ rv[k]=expf(rv[k]-m); s+=rv[k]; }
    #pragma unroll
    for (int k=0;k<9;k++) beta[k][h]=rv[k]/s;
  }
  __syncthreads();
  if (tid < 9) betam[tid] = 0.25f*(beta[tid][0]+beta[tid][1]+beta[tid][2]+beta[tid][3]);
  int h = tid>>5, dd = tid&31;
  float bh[9];
  #pragma unroll
  for (int k=0;k<9;k++) bh[k]=beta[k][h];
  for (int p=0;p<NCA;p++){
    float u=0;
    #pragma unroll
    for (int k=0;k<9;k++){
      int ek = (k<KNNK)? n*KNNK+k : NKE+n;
      u += bh[k]*aVe[ek*1792 + h*448 + p*32 + dd];
    }
    Xs[p][tid] = sspf(u);
  }
  __syncthreads();
  const float* WOt = wt + 3*16384;
  float acc[NCA];
  #pragma unroll
  for (int p=0;p<NCA;p++) acc[p]=0.f;
  for (int c=0;c<HCH;c++){
    float w = WOt[c*128+tid];
    #pragma unroll
    for (int p=0;p<NCA;p++) acc[p] += Xs[p][c]*w;
  }
  int cnt = ccount(res_S[n]);
  for (int p=0;p<NCA;p++){
    float am = (p<cnt)?1.f:0.f;
    float outv = (resHn[(n*NCA+p)*HCH+tid] + acc[p])*am;
    resH2[(n*NCA+p)*HCH+tid] = outv;
  }
  if (tid < NCA*3){
    int isbf = *flag;
    int p=tid/3, jx=tid%3;
    float s=0;
    #pragma unroll
    for (int k=0;k<9;k++){
      int ek=(k<KNNK)? n*KNNK+k : NKE+n;
      s += betam[k]*dXe[(ek*NCA+p)*3+jx];
    }
    float base = cvt[O_RESX+(n*NCA+p)*3+jx];
    float v = (inv_row[n]>=0) ? base + fminf(fmaxf(s,-3.f),3.f) : base;
    resX2[(n*NCA+p)*3+jx] = v;
    storeOut(d_out, isbf, OUTX_OFF + (n*NCA+p)*3+jx, v);
  }
}

// ------------------------------------------------- k6a: ligand-edge logits
__global__ __launch_bounds__(256) void k6a_logits(
    const float* __restrict__ cvt, const int* __restrict__ row1, const int* __restrict__ col1,
    const float* __restrict__ resX2, const float* __restrict__ Qw, const float* __restrict__ Klw,
    float* __restrict__ LG1w)
{
  __shared__ __align__(16) bf16 w1s[8192];
  __shared__ float b1s[128], w2s[512], sb2[4], Xr[42], Lp[96];
  int e = blockIdx.x, tid = threadIdx.x;
  int rr = row1[e] & 255, cb = col1[e] & 3;
  for (int i=tid;i<8192;i+=256) w1s[i] = __float2bfloat16(cvt[O_SD1W1+i]);
  if (tid < 128) b1s[tid]=cvt[O_SD1B1+tid];
  for (int i=tid;i<512;i+=256) w2s[i]=cvt[O_SD1W2+i];
  if (tid < 4) sb2[tid]=cvt[O_SD1B2+tid];
  if (tid >= 8 && tid < 8+42){
    int i=tid-8; int p=i/3, jx=i%3;
    Xr[i] = resX2[(rr*NCA+p)*3+jx];
  }
  if (tid >= 64 && tid < 64+96){
    int i=tid-64; int q=i/3, jx=i%3;
    Lp[i] = cvt[O_LPOS+(cb*LC+q)*3+jx];
  }
  __syncthreads();

  for (int pair=tid; pair<NCA*LC; pair+=256){
    int p = pair>>5, q = pair&31;
    float dx=Xr[p*3]-Lp[q*3], dy=Xr[p*3+1]-Lp[q*3+1], dz=Xr[p*3+2]-Lp[q*3+2];
    float d = sqrtf(fmaxf(dx*dx+dy*dy+dz*dz,1e-12f));
    const float step=10.0f/63.0f; const float coef=-0.5f/(step*step);
    float dr[ECH];
    #pragma unroll
    for (int c=0;c<ECH;c++){ float t=d-step*(float)c; dr[c]=expf(coef*t*t); }
    float sg0=sb2[0],sg1=sb2[1],sg2=sb2[2],sg3=sb2[3];
    for (int o=0;o<HCH;o++){
      float a1=b1s[o];
      const unsigned* wa = ((const unsigned*)w1s) + o*32;
      #pragma unroll
      for (int c2=0;c2<32;c2++){
        unsigned u = wa[c2];
        a1 += dr[2*c2]*bflo(u) + dr[2*c2+1]*bfhi(u);
      }
      a1=fmaxf(a1,0.f);
      sg0+=a1*w2s[o]; sg1+=a1*w2s[128+o]; sg2+=a1*w2s[256+o]; sg3+=a1*w2s[384+o];
    }
    const float* Qp  = Qw  + (rr*NCA+p)*HCH;
    const float* Klp = Klw + (cb*LC+q)*HCH;
    float q0=0,q1=0,q2=0,q3=0;
    #pragma unroll
    for (int dd=0;dd<DH;dd++){
      q0 += Qp[dd]   *Klp[dd];
      q1 += Qp[32+dd]*Klp[32+dd];
      q2 += Qp[64+dd]*Klp[64+dd];
      q3 += Qp[96+dd]*Klp[96+dd];
    }
    const float isq=0.17677669529663687f;
    LG1w[e*1792 + 0*448 + pair] = q0*isq+sg0;
    LG1w[e*1792 + 1*448 + pair] = q1*isq+sg1;
    LG1w[e*1792 + 2*448 + pair] = q2*isq+sg2;
    LG1w[e*1792 + 3*448 + pair] = q3*isq+sg3;
  }
}

// ------------------------------------------------- k6b: ligand-edge softmaxes + aVr + aVlg
__global__ __launch_bounds__(256) void k6b_att(
    const float* __restrict__ cvt, const int* __restrict__ res_S,
    const int* __restrict__ row1, const int* __restrict__ col1,
    const float* __restrict__ LG1w, const float* __restrict__ Vw, const float* __restrict__ Vlw,
    float* __restrict__ r1_ws, float* __restrict__ aVr, float* __restrict__ aVlg)
{
  __shared__ float LG[1792];     // raw logits -> ar (in place)
  __shared__ float ALs[1792];    // al
  __shared__ float Vl[4224];     // Vl[col], stride 132
  __shared__ float Vr[1848];     // V[row], stride 132
  __shared__ float amr[14], lm[32], s2r[56], rpart[56], cnts[2];
  int e = blockIdx.x, tid = threadIdx.x;
  int rr = row1[e] & 255, cb = col1[e] & 3;

  for (int i=tid;i<1792;i+=256) LG[i] = LG1w[e*1792+i];
  for (int i=tid;i<LC*HCH;i+=256){ int q=i>>7, c=i&127; Vl[q*132+c] = Vlw[cb*LC*HCH + i]; }
  for (int i=tid;i<NCA*HCH;i+=256){ int p=i>>7, c=i&127; Vr[p*132+c] = Vw[rr*NCA*HCH + i]; }
  if (tid < NCA) amr[tid] = (tid < ccount(res_S[rr])) ? 1.f : 0.f;
  if (tid >= 32 && tid < 64) lm[tid-32] = cvt[O_LMASK + cb*LC + tid-32];
  __syncthreads();

  if (tid < 56){
    int h=tid/14, pp=tid%14;
    float ap=amr[pp];
    float s=0, m=-INFINITY;
    for (int qq=0;qq<LC;qq++){ float v=LG[h*448+pp*32+qq]; s+=v*lm[qq]; m=fmaxf(m,v); }
    rpart[h*14+pp]=s*ap;
    float sum=0;
    for (int qq=0;qq<LC;qq++) sum+=expf(LG[h*448+pp*32+qq]-m);
    float inv=1.f/sum, s2=0;
    for (int qq=0;qq<LC;qq++) s2 += expf(LG[h*448+pp*32+qq]-m)*inv*ap*lm[qq];
    s2r[h*14+pp] = s2/(s2+1e-7f);   // = sum_q |ar_final|
  }
  if (tid==56){
    float sr=0,sl=0;
    for(int i=0;i<NCA;i++) sr+=amr[i];
    for(int i=0;i<LC;i++) sl+=lm[i];
    cnts[0]=sr; cnts[1]=sl;
  }
  __syncthreads();
  if (tid < NH){
    float s=0; for (int pp=0;pp<NCA;pp++) s+=rpart[tid*14+pp];
    r1_ws[e*NH+tid]=s/(cnts[0]*cnts[1]);
  }
  if (tid < NH*LC){
    int h=tid>>5, qq=tid&31;
    float m=-INFINITY;
    for (int pp=0;pp<NCA;pp++) m=fmaxf(m,LG[h*448+pp*32+qq]);
    float sum=0;
    for (int pp=0;pp<NCA;pp++) sum+=expf(LG[h*448+pp*32+qq]-m);
    float inv=1.f/sum;
    float lq=lm[qq];
    for (int pp=0;pp<NCA;pp++){
      float a=expf(LG[h*448+pp*32+qq]-m)*inv*amr[pp]*lq;
      ALs[h*448+pp*32+qq]=a/(s2r[h*14+pp]+1e-7f);
    }
  }
  __syncthreads();
  if (tid < 56){
    int h=tid/14, pp=tid%14;
    float ap=amr[pp];
    float m=-INFINITY;
    for (int qq=0;qq<LC;qq++) m=fmaxf(m,LG[h*448+pp*32+qq]);
    float row[LC];
    float sum=0;
    for (int qq=0;qq<LC;qq++){ row[qq]=expf(LG[h*448+pp*32+qq]-m); sum+=row[qq]; }
    float inv=1.f/sum, s2=0;
    for (int qq=0;qq<LC;qq++){ row[qq]=row[qq]*inv*ap*lm[qq]; s2+=row[qq]; }
    float inv2=1.f/(s2+1e-7f);
    for (int qq=0;qq<LC;qq++) LG[h*448+pp*32+qq]=row[qq]*inv2;
  }
  __syncthreads();
  for (int j=tid;j<NH*NCA*DH;j+=256){
    int h=j/448, rem=j%448, pp=rem>>5, dd=rem&31;
    float acc=0;
    #pragma unroll
    for (int qq=0;qq<LC;qq++) acc += LG[h*448+pp*32+qq]*Vl[qq*132+h*32+dd];
    aVr[e*1792+j]=acc;
  }
  for (int j=tid;j<NH*LC*DH;j+=256){
    int h=j>>10, rem=j&1023, qq=rem>>5, dd=rem&31;
    float acc=0;
    #pragma unroll
    for (int pp=0;pp<NCA;pp++) acc += ALs[h*448+pp*32+qq]*Vr[pp*132+h*32+dd];
    aVlg[e*4096+j]=acc;
  }
}

// ------------------------------------------------- k7: finalize res_H3
__global__ __launch_bounds__(128) void k7_finalH(
    const int* __restrict__ inv_row, const int* __restrict__ res_S,
    const float* __restrict__ resH2, const float* __restrict__ aVr,
    const float* __restrict__ wt, const int* __restrict__ flag, void* __restrict__ d_out)
{
  int n=blockIdx.x, tid=threadIdx.x;
  int e = inv_row[n];
  __shared__ float G[NCA][HCH];
  if (e>=0){
    for (int j=tid;j<NCA*HCH;j+=128){
      int h=j/448, rem=j%448, pp=rem>>5, dd=rem&31;
      G[pp][h*DH+dd] = sspf(aVr[e*1792+j]);
    }
  }
  __syncthreads();
  float acc[NCA];
  #pragma unroll
  for (int p=0;p<NCA;p++) acc[p]=0.f;
  if (e>=0){
    const float* WOlt = wt + 6*16384;
    for (int c=0;c<HCH;c++){
      float w=WOlt[c*128+tid];
      #pragma unroll
      for (int p=0;p<NCA;p++) acc[p]+=G[p][c]*w;
    }
  }
  int cnt=ccount(res_S[n]);
  int isbf = *flag;
  for (int p=0;p<NCA;p++){
    float am=(p<cnt)?1.f:0.f;
    float v=(resH2[(n*NCA+p)*HCH+tid]+acc[p])*am;
    storeOut(d_out, isbf, (n*NCA+p)*HCH+tid, v);
  }
}

// ------------------------------------------------- k8: beta1 + updL + WOl1 -> lf2
__global__ __launch_bounds__(128) void k8_lf2(
    const int* __restrict__ col1, const float* __restrict__ r1_ws, const float* __restrict__ aVlg,
    const float* __restrict__ lf, const float* __restrict__ wt, const int* __restrict__ flag,
    void* __restrict__ d_out)
{
  int rb=blockIdx.x, tid=threadIdx.x;
  int b=rb>>5, q=rb&31;
  __shared__ float bw[NE1][NH];
  __shared__ float xs[HCH];
  if (tid<NH){
    int h=tid;
    float m=-INFINITY;
    for (int e=0;e<NE1;e++) if ((col1[e]&3)==b) m=fmaxf(m, r1_ws[e*NH+h]);
    float s=0;
    for (int e=0;e<NE1;e++) if ((col1[e]&3)==b) s+=expf(r1_ws[e*NH+h]-m);
    for (int e=0;e<NE1;e++) bw[e][h] = ((col1[e]&3)==b)? expf(r1_ws[e*NH+h]-m)/s : 0.f;
  }
  __syncthreads();
  int h=tid>>5, dd=tid&31;
  float u=0;
  for (int e=0;e<NE1;e++) u += bw[e][h]*aVlg[e*4096 + h*1024 + q*32 + dd];
  xs[tid]=sspf(u);
  __syncthreads();
  const float* WOl1t = wt + 7*16384;
  float acc=0;
  for (int c=0;c<HCH;c++) acc += xs[c]*WOl1t[c*128+tid];
  float v = lf[rb*HCH+tid] + acc;
  storeOut(d_out, *flag, OUTL_OFF + rb*HCH+tid, v);
}

// ================================================================ launch
extern "C" void kernel_launch(void* const* d_in, const int* in_sizes, int n_in,
                              void* d_out, int out_size, void* d_ws, size_t ws_size,
                              hipStream_t stream)
{
  const int* res_S = (const int*)d_in[29];
  const int* batch = (const int*)d_in[30];
  // d_in[31] residue_mask (bool) intentionally unused — reconstructed from row1
  const int* row1  = (const int*)d_in[32];
  const int* col1  = (const int*)d_in[33];

  float* wsf = (float*)d_ws;
  size_t o = 0;
  int*   flag    = (int*)(wsf + o); o += 4;
  float* cvt     = wsf + o; o += CVT_RSV;
  float* wt      = wsf + o; o += 10*16384;
  int*   inv_row = (int*)(wsf + o); o += 256;
  int*   nbr     = (int*)(wsf + o); o += NRES*KNNK;
  float* resHn   = wsf + o; o += NRES*NCA*HCH;
  float* Qw      = wsf + o; o += NRES*NCA*HCH;
  float* Kw      = wsf + o; o += NRES*NCA*HCH;
  float* Vw      = wsf + o; o += NRES*NCA*HCH;
  float* TQw     = wsf + o; o += NRES*NCA*HCH;
  float* TKw     = wsf + o; o += NRES*NCA*HCH;
  float* r_ws    = wsf + o; o += NEDGE*NH;
  float* aVe     = wsf + o; o += (size_t)NEDGE*1792;
  float* dXe     = wsf + o; o += NEDGE*NCA*3;
  float* resH2   = wsf + o; o += NRES*NCA*HCH;
  float* resX2   = wsf + o; o += NRES*NCA*3;
  float* lf      = wsf + o; o += 4*LC*HCH;
  float* Klw     = wsf + o; o += 4*LC*HCH;
  float* Vlw     = wsf + o; o += 4*LC*HCH;
  float* r1w     = wsf + o; o += NE1*NH;
  float* aVrw    = wsf + o; o += NE1*1792;
  float* aVlgw   = wsf + o; o += NE1*4096;
  float* LGw     = wsf + o; o += (size_t)NEDGE*784;
  float* FRw     = wsf + o; o += NEDGE*196;
  float* LG1w    = wsf + o; o += NE1*1792;
  // total ~44.4 MB

  kdet<<<1, 64, 0, stream>>>((const unsigned*)d_in[0], flag);
  kcvt<<<(TOTCVT+255)/256, 256, 0, stream>>>(flag,
      d_in[0],d_in[1],d_in[2],d_in[3],d_in[4],d_in[5],d_in[6],d_in[7],d_in[8],
      d_in[9],d_in[10],d_in[11],d_in[12],d_in[13],d_in[14],d_in[15],d_in[16],
      d_in[17],d_in[18],d_in[19],d_in[20],d_in[21],d_in[22],d_in[23],d_in[24],
      d_in[25],d_in[26],d_in[27],d_in[28], cvt);
  k0_prep<<<641, 256, 0, stream>>>(cvt, row1, wt, inv_row);
  k1_res_proj<<<NRES, 128, 0, stream>>>(cvt, wt, resHn, Qw, Kw, Vw, TQw, TKw);
  k2_knn<<<NRES, 256, 0, stream>>>(cvt, batch, nbr);
  k5_ligproj<<<4*LC, 128, 0, stream>>>(cvt, wt, lf, Klw, Vlw);
  k3a_logits<<<NEDGE, 256, 0, stream>>>(cvt, nbr, Qw, Kw, TQw, TKw, LGw, FRw);
  k3b_att<<<NEDGE, 256, 0, stream>>>(cvt, res_S, nbr, LGw, FRw, Vw, r_ws, aVe, dXe);
  k4_agg<<<NRES, 128, 0, stream>>>(cvt, res_S, inv_row, r_ws, aVe, dXe, resHn, wt, flag,
                                   resH2, resX2, d_out);
  k6a_logits<<<NE1, 256, 0, stream>>>(cvt, row1, col1, resX2, Qw, Klw, LG1w);
  k6b_att<<<NE1, 256, 0, stream>>>(cvt, res_S, row1, col1, LG1w, Vw, Vlw, r1w, aVrw, aVlgw);
  k7_finalH<<<NRES, 128, 0, stream>>>(inv_row, res_S, resH2, aVrw, wt, flag, d_out);
  k8_lf2<<<4*LC, 128, 0, stream>>>(col1, r1w, aVlgw, lf, wt, flag, d_out);
}

// Round 4
// 389.096 us; speedup vs baseline: 2.5178x; 2.5178x over previous
//
#include <hip/hip_runtime.h>
#include <hip/hip_bf16.h>
#include <math.h>

typedef __hip_bfloat16 bf16;

#define NRES 256
#define LC   32
#define HCH  128
#define ECH  64
#define NH   4
#define NCA  14
#define KNNK 8
#define DH   32
#define NKE  (NRES*KNNK)      // 2048
#define NEDGE (NKE+NRES)      // 2304
#define NE1  64

// distance tables: nearest-neighbor, h=1/256, domain [0,12]
#define NT     3073
#define TSCALE 256.0f
#define DMAXT  12.0f

// ---- fp32 converted-input region offsets (floats) ----
#define O_RESH   0
#define O_RESX   458752
#define O_LPOS   469504
#define O_LFEAT  469888
#define O_LMASK  486272
#define O_LNG    486400
#define O_LNB    486528
#define O_LN1G   486656
#define O_LN1B   486784
#define O_WQ     486912
#define O_WK     503296
#define O_WV     519680
#define O_WKL    536064
#define O_WVL    552448
#define O_WO     568832
#define O_WOL    585216
#define O_WOL1   601600
#define O_TIW1   617984
#define O_TIB1   658944
#define O_TIW2   659072
#define O_TIB2   659200
#define O_SDW1   659204
#define O_SDB1   667396
#define O_SDW2   667524
#define O_SDB2   668036
#define O_SD1W1  668040
#define O_SD1B1  676232
#define O_SD1W2  676360
#define O_SD1B2  676872
#define TOTCVT   676876
#define CVT_RSV  676880

#define OUTX_OFF 458752
#define OUTL_OFF 469504

__constant__ int c_counts[21] = {14,5,11,8,8,6,9,9,4,10,8,8,9,8,11,7,6,7,14,12,7};

__device__ __forceinline__ float b2f(bf16 x){ return __bfloat162float(x); }
__device__ __forceinline__ float sspf(float x){
  return fmaxf(x,0.f) + log1pf(expf(-fabsf(x))) - 0.6931471805599453f;
}
__device__ __forceinline__ int ccount(int s){ return c_counts[s<0?0:(s>20?20:s)]; }
__device__ __forceinline__ void storeOut(void* out, int isbf, int idx, float v){
  if (isbf) ((bf16*)out)[idx] = __float2bfloat16(v);
  else      ((float*)out)[idx] = v;
}

// ---------------------------------------------------------------- kdet: detect input float dtype
__global__ __launch_bounds__(64) void kdet(const unsigned* __restrict__ resH_raw, int* __restrict__ flag)
{
  int tid = threadIdx.x;
  unsigned w = resH_raw[tid];
  unsigned lo = w & 0xFFFFu;
  int e = (lo >> 7) & 0xFF;
  int good = (lo == 0u) || (e >= 121 && e <= 133);
  unsigned long long m = __ballot(good);
  if (tid == 0) flag[0] = (__popcll(m) >= 40) ? 1 : 0;   // 1 = inputs are bf16
}

// ---------------------------------------------------------------- kcvt: all float inputs -> fp32 copies
__global__ __launch_bounds__(256) void kcvt(
    const int* __restrict__ flag,
    const void* s0,const void* s1,const void* s2,const void* s3,const void* s4,
    const void* s5,const void* s6,const void* s7,const void* s8,const void* s9,
    const void* s10,const void* s11,const void* s12,const void* s13,const void* s14,
    const void* s15,const void* s16,const void* s17,const void* s18,const void* s19,
    const void* s20,const void* s21,const void* s22,const void* s23,const void* s24,
    const void* s25,const void* s26,const void* s27,const void* s28,
    float* __restrict__ dst)
{
  int g = blockIdx.x*256 + threadIdx.x;
  if (g >= TOTCVT) return;
  const void* src; int l;
  if      (g < O_RESX ) { src=s0;  l=g; }
  else if (g < O_LPOS ) { src=s1;  l=g-O_RESX; }
  else if (g < O_LFEAT) { src=s2;  l=g-O_LPOS; }
  else if (g < O_LMASK) { src=s3;  l=g-O_LFEAT; }
  else if (g < O_LNG  ) { src=s4;  l=g-O_LMASK; }
  else if (g < O_LNB  ) { src=s5;  l=g-O_LNG; }
  else if (g < O_LN1G ) { src=s6;  l=g-O_LNB; }
  else if (g < O_LN1B ) { src=s7;  l=g-O_LN1G; }
  else if (g < O_WQ   ) { src=s8;  l=g-O_LN1B; }
  else if (g < O_WK   ) { src=s9;  l=g-O_WQ; }
  else if (g < O_WV   ) { src=s10; l=g-O_WK; }
  else if (g < O_WKL  ) { src=s11; l=g-O_WV; }
  else if (g < O_WVL  ) { src=s12; l=g-O_WKL; }
  else if (g < O_WO   ) { src=s13; l=g-O_WVL; }
  else if (g < O_WOL  ) { src=s14; l=g-O_WO; }
  else if (g < O_WOL1 ) { src=s15; l=g-O_WOL; }
  else if (g < O_TIW1 ) { src=s16; l=g-O_WOL1; }
  else if (g < O_TIB1 ) { src=s17; l=g-O_TIW1; }
  else if (g < O_TIW2 ) { src=s18; l=g-O_TIB1; }
  else if (g < O_TIB2 ) { src=s19; l=g-O_TIW2; }
  else if (g < O_SDW1 ) { src=s20; l=0; }
  else if (g < O_SDB1 ) { src=s21; l=g-O_SDW1; }
  else if (g < O_SDW2 ) { src=s22; l=g-O_SDB1; }
  else if (g < O_SDB2 ) { src=s23; l=g-O_SDW2; }
  else if (g < O_SD1W1) { src=s24; l=g-O_SDB2; }
  else if (g < O_SD1B1) { src=s25; l=g-O_SD1W1; }
  else if (g < O_SD1W2) { src=s26; l=g-O_SD1B1; }
  else if (g < O_SD1B2) { src=s27; l=g-O_SD1W2; }
  else                  { src=s28; l=g-O_SD1B2; }
  float v = (*flag) ? b2f(((const bf16*)src)[l]) : ((const float*)src)[l];
  dst[g] = v;
}

// ---------------------------------------------------------------- ktab: distance-function tables
// cT[i][o]  = Ti_b1[o] + drep(d_i) @ Ti_w1[o, 256:]         (128 per entry)
// sigT[i][h]  = sD MLP output h at d_i   (full 64->128->relu->4)
// sig1T[i][h] = sD1 MLP output h at d_i
__global__ __launch_bounds__(128) void ktab(const float* __restrict__ cvt,
    float* __restrict__ cT, float* __restrict__ sigT, float* __restrict__ sig1T)
{
  int i = blockIdx.x, o = threadIdx.x;
  __shared__ float dr[64];
  __shared__ float W[128*65];      // padded stride 65: banks (o+k)%32, conflict-free
  __shared__ float h1[128], h1b[128];
  float d = (float)i * (1.0f/256.0f);
  const float step = 10.0f/63.0f;
  const float coef = -0.5f/(step*step);
  if (o < 64){ float t = d - step*(float)o; dr[o] = expf(coef*t*t); }
  for (int idx=o; idx<8192; idx+=128){ int oo=idx>>6, k=idx&63; W[oo*65+k] = cvt[O_TIW1 + oo*320 + 256 + k]; }
  __syncthreads();
  {
    float c = cvt[O_TIB1+o];
    for (int k=0;k<64;k++) c += dr[k]*W[o*65+k];
    cT[i*128+o] = c;
  }
  __syncthreads();
  for (int idx=o; idx<8192; idx+=128){ int oo=idx>>6, k=idx&63; W[oo*65+k] = cvt[O_SDW1 + idx]; }
  __syncthreads();
  {
    float a = cvt[O_SDB1+o];
    for (int k=0;k<64;k++) a += dr[k]*W[o*65+k];
    h1[o] = fmaxf(a,0.f);
  }
  __syncthreads();
  for (int idx=o; idx<8192; idx+=128){ int oo=idx>>6, k=idx&63; W[oo*65+k] = cvt[O_SD1W1 + idx]; }
  __syncthreads();
  {
    float a2 = cvt[O_SD1B1+o];
    for (int k=0;k<64;k++) a2 += dr[k]*W[o*65+k];
    h1b[o] = fmaxf(a2,0.f);
  }
  __syncthreads();
  if (o < 8){
    int h = o & 3;
    const float* hh = (o<4)? h1 : h1b;
    int wbase = (o<4)? O_SDW2 : O_SD1W2;
    int bbase = (o<4)? O_SDB2 : O_SD1B2;
    float s = cvt[bbase + h];
    for (int k=0;k<128;k++) s += hh[k]*cvt[wbase + h*128 + k];
    if (o<4) sigT[i*4+h] = s; else sig1T[i*4+h] = s;
  }
}

// ---------------------------------------------------------------- k0: transpose weights + inv_row
__global__ __launch_bounds__(256) void k0_prep(
    const float* __restrict__ cvt, const int* __restrict__ row1,
    float* __restrict__ wt, int* __restrict__ inv_row)
{
  int bid = blockIdx.x, tid = threadIdx.x;
  if (bid == 640){
    if (tid < NRES) inv_row[tid] = -1;
    __syncthreads();
    if (tid < NE1) inv_row[row1[tid] & 255] = tid;
    return;
  }
  int gid = bid*256 + tid;
  int m = gid >> 14;
  int j = gid & 16383;
  int o = j >> 7, c = j & 127;
  float v;
  switch(m){
    case 0: v = cvt[O_WQ  + j]; break;
    case 1: v = cvt[O_WK  + j]; break;
    case 2: v = cvt[O_WV  + j]; break;
    case 3: v = cvt[O_WO  + j]; break;
    case 4: v = cvt[O_WKL + j]; break;
    case 5: v = cvt[O_WVL + j]; break;
    case 6: v = cvt[O_WOL + j]; break;
    case 7: v = cvt[O_WOL1+ j]; break;
    case 8: v = cvt[O_TIW1 + o*320 + c]; break;
    default:v = cvt[O_TIW1 + o*320 + 128 + c]; break;
  }
  wt[m*16384 + c*128 + o] = v;
}

// ------------------------------------------------- k1: residue LN + 5 projections
__global__ __launch_bounds__(128) void k1_res_proj(
    const float* __restrict__ cvt, const float* __restrict__ wt, float* __restrict__ resHn,
    float* __restrict__ Qw, float* __restrict__ Kw, float* __restrict__ Vw,
    float* __restrict__ TQw, float* __restrict__ TKw)
{
  int n = blockIdx.x, tid = threadIdx.x;
  __shared__ float xr[NCA][HCH];
  __shared__ float qr[NCA][HCH];
  __shared__ float kr[NCA][HCH];
  __shared__ float sred[2];
  float g = cvt[O_LNG+tid], bb = cvt[O_LNB+tid];
  for (int p=0;p<NCA;p++){
    float v = cvt[O_RESH + (n*NCA+p)*HCH + tid];
    float s = v;
    for (int off=1; off<64; off<<=1) s += __shfl_xor(s, off);
    if ((tid&63)==0) sred[tid>>6] = s;
    __syncthreads();
    float mu = (sred[0]+sred[1])*(1.f/HCH);
    __syncthreads();
    float d = v-mu;
    s = d*d;
    for (int off=1; off<64; off<<=1) s += __shfl_xor(s, off);
    if ((tid&63)==0) sred[tid>>6] = s;
    __syncthreads();
    float var = (sred[0]+sred[1])*(1.f/HCH);
    __syncthreads();
    float xh = d*rsqrtf(var+1e-5f)*g + bb;
    xr[p][tid] = xh;
    resHn[(n*NCA+p)*HCH + tid] = xh;
  }
  __syncthreads();
  const float* WQt = wt;
  const float* WKt = wt + 16384;
  const float* WVt = wt + 2*16384;
  const float* TQt = wt + 8*16384;
  const float* TKt = wt + 9*16384;
  {
    float aQ[NCA], aK[NCA], aV[NCA];
    #pragma unroll
    for (int p=0;p<NCA;p++){ aQ[p]=0.f; aK[p]=0.f; aV[p]=0.f; }
    for (int c=0;c<HCH;c++){
      float wq = WQt[c*128+tid], wk = WKt[c*128+tid], wv = WVt[c*128+tid];
      #pragma unroll
      for (int p=0;p<NCA;p++){
        float x = xr[p][c];
        aQ[p] += x*wq; aK[p] += x*wk; aV[p] += x*wv;
      }
    }
    for (int p=0;p<NCA;p++){
      qr[p][tid] = aQ[p]; kr[p][tid] = aK[p];
      Qw[(n*NCA+p)*HCH+tid] = aQ[p];
      Kw[(n*NCA+p)*HCH+tid] = aK[p];
      Vw[(n*NCA+p)*HCH+tid] = aV[p];
    }
  }
  __syncthreads();
  {
    float aTQ[NCA], aTK[NCA];
    #pragma unroll
    for (int p=0;p<NCA;p++){ aTQ[p]=0.f; aTK[p]=0.f; }
    for (int c=0;c<HCH;c++){
      float wtq = TQt[c*128+tid], wtk = TKt[c*128+tid];
      #pragma unroll
      for (int p=0;p<NCA;p++){
        aTQ[p] += qr[p][c]*wtq; aTK[p] += kr[p][c]*wtk;
      }
    }
    for (int p=0;p<NCA;p++){
      TQw[(n*NCA+p)*HCH+tid] = aTQ[p];
      TKw[(n*NCA+p)*HCH+tid] = aTK[p];
    }
  }
}

// ------------------------------------------------- k2: KNN (replicates lax.top_k tie-break)
__global__ __launch_bounds__(256) void k2_knn(
    const float* __restrict__ cvt, const int* __restrict__ batch, int* __restrict__ nbr)
{
  int n = blockIdx.x, j = threadIdx.x;
  __shared__ float sd[256];
  __shared__ float rd[256];
  __shared__ int   ri[256];
  float cx = cvt[O_RESX+(n*NCA+1)*3+0];
  float cy = cvt[O_RESX+(n*NCA+1)*3+1];
  float cz = cvt[O_RESX+(n*NCA+1)*3+2];
  float jx = cvt[O_RESX+(j*NCA+1)*3+0];
  float jy = cvt[O_RESX+(j*NCA+1)*3+1];
  float jz = cvt[O_RESX+(j*NCA+1)*3+2];
  float dx=cx-jx, dy=cy-jy, dz=cz-jz;
  float d2 = dx*dx+dy*dy+dz*dz;
  bool bad = (batch[j]!=batch[n]) || (j==n);
  sd[j] = bad ? INFINITY : d2;
  __syncthreads();
  for (int k=0;k<KNNK;k++){
    rd[j]=sd[j]; ri[j]=j;
    __syncthreads();
    for (int off=128; off>0; off>>=1){
      if (j<off){
        float da=rd[j], db=rd[j+off];
        int ia=ri[j], ib=ri[j+off];
        if (db<da || (db==da && ib<ia)){ rd[j]=db; ri[j]=ib; }
      }
      __syncthreads();
    }
    if (j==0){ nbr[n*KNNK+k]=ri[0]; sd[ri[0]] = INFINITY; }
    __syncthreads();
  }
}

// ------------------------------------------------- k5: ligand LN + Kl/Vl projections
__global__ __launch_bounds__(128) void k5_ligproj(
    const float* __restrict__ cvt, const float* __restrict__ wt, float* __restrict__ lf,
    float* __restrict__ Klw, float* __restrict__ Vlw)
{
  int rb = blockIdx.x, tid = threadIdx.x;
  __shared__ float x[HCH];
  __shared__ float sred[2];
  float v = cvt[O_LFEAT + rb*HCH + tid];
  float s=v;
  for (int off=1; off<64; off<<=1) s += __shfl_xor(s, off);
  if ((tid&63)==0) sred[tid>>6]=s;
  __syncthreads();
  float mu=(sred[0]+sred[1])*(1.f/HCH);
  __syncthreads();
  float d=v-mu; s=d*d;
  for (int off=1; off<64; off<<=1) s += __shfl_xor(s, off);
  if ((tid&63)==0) sred[tid>>6]=s;
  __syncthreads();
  float var=(sred[0]+sred[1])*(1.f/HCH);
  float xh = d*rsqrtf(var+1e-5f)*cvt[O_LN1G+tid] + cvt[O_LN1B+tid];
  x[tid]=xh; lf[rb*HCH+tid]=xh;
  __syncthreads();
  const float* WKlt = wt + 4*16384;
  const float* WVlt = wt + 5*16384;
  float aK=0.f, aV=0.f;
  for (int c=0;c<HCH;c++){
    float xc=x[c];
    aK += xc*WKlt[c*128+tid];
    aV += xc*WVlt[c*128+tid];
  }
  Klw[rb*HCH+tid]=aK; Vlw[rb*HCH+tid]=aV;
}

// ------------------------------------------------- k3a: residue-edge logits via distance tables
__global__ __launch_bounds__(256) void k3a_logits(
    const float* __restrict__ cvt, const int* __restrict__ nbr,
    const float* __restrict__ Qw, const float* __restrict__ Kw,
    const float* __restrict__ TQw, const float* __restrict__ TKw,
    const float* __restrict__ cT, const float* __restrict__ sigT,
    float* __restrict__ LGw, float* __restrict__ FRw)
{
  __shared__ float Bq[1848], Bk[1848], Tq[1848], Tk[1848];   // stride 132
  __shared__ float tw2s[128], tb2s[1], Xr[42], Xc[42];
  int e = blockIdx.x, tid = threadIdx.x;
  int rr, cc;
  if (e < NKE){ rr = e >> 3; cc = nbr[e] & 255; } else { rr = e - NKE; cc = rr; }

  for (int i=tid;i<NCA*HCH;i+=256){
    int p=i>>7, c=i&127;
    Bq[p*132+c]=Qw[rr*1792+i];  Bk[p*132+c]=Kw[cc*1792+i];
    Tq[p*132+c]=TQw[rr*1792+i]; Tk[p*132+c]=TKw[cc*1792+i];
  }
  if (tid < 128) tw2s[tid]=cvt[O_TIW2+tid];
  if (tid == 128) tb2s[0]=cvt[O_TIB2];
  if (tid >= 136 && tid < 178){
    int i=tid-136; int p=i/3, jx=i%3;
    Xr[i] = cvt[O_RESX+(rr*NCA+p)*3+jx];
    Xc[i] = cvt[O_RESX+(cc*NCA+p)*3+jx];
  }
  __syncthreads();

  if (tid < 196){
    int p = tid/14, q = tid%14;
    float dx=Xr[p*3]-Xc[q*3], dy=Xr[p*3+1]-Xc[q*3+1], dz=Xr[p*3+2]-Xc[q*3+2];
    float d = sqrtf(fmaxf(dx*dx+dy*dy+dz*dz, 1e-12f));
    int i0 = (int)(fminf(d, DMAXT)*TSCALE + 0.5f);
    float4 sg = ((const float4*)sigT)[i0];
    const float4* crow = (const float4*)(cT + i0*128);
    float fa = tb2s[0];
    #pragma unroll 8
    for (int j=0;j<32;j++){
      float4 cb = crow[j];
      int o = 4*j;
      fa += fmaxf(Tq[p*132+o  ]+Tk[q*132+o  ]+cb.x, 0.f)*tw2s[o  ];
      fa += fmaxf(Tq[p*132+o+1]+Tk[q*132+o+1]+cb.y, 0.f)*tw2s[o+1];
      fa += fmaxf(Tq[p*132+o+2]+Tk[q*132+o+2]+cb.z, 0.f)*tw2s[o+2];
      fa += fmaxf(Tq[p*132+o+3]+Tk[q*132+o+3]+cb.w, 0.f)*tw2s[o+3];
    }
    float qk0=0,qk1=0,qk2=0,qk3=0;
    #pragma unroll
    for (int dd=0;dd<DH;dd++){
      qk0 += Bq[p*132+dd]   *Bk[q*132+dd];
      qk1 += Bq[p*132+32+dd]*Bk[q*132+32+dd];
      qk2 += Bq[p*132+64+dd]*Bk[q*132+64+dd];
      qk3 += Bq[p*132+96+dd]*Bk[q*132+96+dd];
    }
    const float isq = 0.17677669529663687f;   // 1/sqrt(32)
    LGw[e*784 + 0*196 + tid] = qk0*isq + sg.x;
    LGw[e*784 + 1*196 + tid] = qk1*isq + sg.y;
    LGw[e*784 + 2*196 + tid] = qk2*isq + sg.z;
    LGw[e*784 + 3*196 + tid] = qk3*isq + sg.w;
    FRw[e*196 + tid] = fa;
  }
}

// ------------------------------------------------- k3b: residue-edge softmax / r / aV / dX
__global__ __launch_bounds__(256) void k3b_att(
    const float* __restrict__ cvt, const int* __restrict__ res_S, const int* __restrict__ nbr,
    const float* __restrict__ LGw, const float* __restrict__ FRw, const float* __restrict__ Vw,
    float* __restrict__ r_ws, float* __restrict__ aVe, float* __restrict__ dXe)
{
  __shared__ float LG[784];
  __shared__ float FR[196];
  __shared__ float Vc[1848];
  __shared__ float Xr[42], Xc[42], amr[14], amc[14], rpart[56], cnts[2];
  int e = blockIdx.x, tid = threadIdx.x;
  int rr, cc;
  if (e < NKE){ rr = e >> 3; cc = nbr[e] & 255; } else { rr = e - NKE; cc = rr; }

  for (int i=tid;i<784;i+=256) LG[i] = LGw[e*784+i];
  if (tid < 196) FR[tid] = FRw[e*196+tid];
  for (int i=tid;i<NCA*HCH;i+=256){
    int p=i>>7, c=i&127;
    Vc[p*132+c] = Vw[cc*NCA*HCH + i];
  }
  if (tid >= 196 && tid < 196+42){
    int i=tid-196; int p=i/3, jx=i%3;
    Xr[i] = cvt[O_RESX+(rr*NCA+p)*3+jx];
    Xc[i] = cvt[O_RESX+(cc*NCA+p)*3+jx];
  }
  if (tid >= 242 && tid < 242+NCA){
    int p=tid-242;
    amr[p] = (p < ccount(res_S[rr])) ? 1.f : 0.f;
    amc[p] = (p < ccount(res_S[cc])) ? 1.f : 0.f;
  }
  __syncthreads();

  if (tid < 56){
    int h=tid/14, pp=tid%14;
    float ap = amr[pp];
    float row[NCA];
    float s=0;
    #pragma unroll
    for (int qq=0;qq<NCA;qq++){ row[qq]=LG[h*196+pp*14+qq]; s += row[qq]*amc[qq]; }
    rpart[h*14+pp] = s*ap;
    float m=-INFINITY;
    #pragma unroll
    for (int qq=0;qq<NCA;qq++) m=fmaxf(m,row[qq]);
    float sum=0;
    #pragma unroll
    for (int qq=0;qq<NCA;qq++){ row[qq]=expf(row[qq]-m); sum+=row[qq]; }
    float inv=1.f/sum, s2=0;
    #pragma unroll
    for (int qq=0;qq<NCA;qq++){ row[qq]=row[qq]*inv*ap*amc[qq]; s2+=row[qq]; }
    float inv2=1.f/(s2+1e-7f);
    #pragma unroll
    for (int qq=0;qq<NCA;qq++) LG[h*196+pp*14+qq]=row[qq]*inv2;
  }
  if (tid == 56){
    float sr=0, sc=0;
    for (int i=0;i<NCA;i++){ sr+=amr[i]; sc+=amc[i]; }
    cnts[0]=sr; cnts[1]=sc;
  }
  __syncthreads();
  if (tid < NH){
    float s=0;
    for (int pp=0;pp<NCA;pp++) s += rpart[tid*14+pp];
    r_ws[e*NH+tid] = s/(cnts[0]*cnts[1]);
  }
  if (tid < 196){
    int p=tid/14, q=tid%14;
    float ma = 0.25f*(LG[p*14+q] + LG[196+p*14+q] + LG[392+p*14+q] + LG[588+p*14+q]);
    FR[tid] *= ma;
  }
  __syncthreads();
  if (tid < NCA){
    int pp=tid;
    float ax=0, ay=0, az=0;
    #pragma unroll
    for (int qq=0;qq<NCA;qq++){
      float dx=Xr[pp*3]-Xc[qq*3], dy=Xr[pp*3+1]-Xc[qq*3+1], dz=Xr[pp*3+2]-Xc[qq*3+2];
      float nrm = sqrtf(fmaxf(dx*dx+dy*dy+dz*dz,1e-12f));
      float sc = FR[pp*14+qq]/(nrm+1e-5f);
      ax += sc*dx; ay += sc*dy; az += sc*dz;
    }
    dXe[(e*NCA+pp)*3+0]=ax; dXe[(e*NCA+pp)*3+1]=ay; dXe[(e*NCA+pp)*3+2]=az;
  }
  #pragma unroll
  for (int rep=0;rep<7;rep++){
    int jdx = rep*256 + tid;
    int h = jdx/448, rem = jdx%448;
    int pp = rem>>5, dd = rem&31;
    float acc=0;
    #pragma unroll
    for (int qq=0;qq<NCA;qq++) acc += LG[h*196+pp*14+qq]*Vc[qq*132 + h*32 + dd];
    aVe[e*1792 + jdx] = acc;
  }
}

// ------------------------------------------------- k4: per-residue beta + updH + WO + dX
__global__ __launch_bounds__(128) void k4_agg(
    const float* __restrict__ cvt, const int* __restrict__ res_S, const int* __restrict__ inv_row,
    const float* __restrict__ r_ws, const float* __restrict__ aVe, const float* __restrict__ dXe,
    const float* __restrict__ resHn, const float* __restrict__ wt, const int* __restrict__ flag,
    float* __restrict__ resH2, float* __restrict__ resX2, void* __restrict__ d_out)
{
  int n = blockIdx.x, tid = threadIdx.x;
  __shared__ float beta[9][NH];
  __shared__ float betam[9];
  __shared__ float Xs[NCA][HCH];
  if (tid < NH){
    int h = tid;
    float rv[9], m=-INFINITY;
    #pragma unroll
    for (int k=0;k<9;k++){
      int ek = (k<KNNK)? n*KNNK+k : NKE+n;
      rv[k] = r_ws[ek*NH+h];
      m = fmaxf(m, rv[k]);
    }
    float s=0;
    #pragma unroll
    for (int k=0;k<9;k++){ rv[k]=expf(rv[k]-m); s+=rv[k]; }
    #pragma unroll
    for (int k=0;k<9;k++) beta[k][h]=rv[k]/s;
  }
  __syncthreads();
  if (tid < 9) betam[tid] = 0.25f*(beta[tid][0]+beta[tid][1]+beta[tid][2]+beta[tid][3]);
  int h = tid>>5, dd = tid&31;
  float bh[9];
  #pragma unroll
  for (int k=0;k<9;k++) bh[k]=beta[k][h];
  for (int p=0;p<NCA;p++){
    float u=0;
    #pragma unroll
    for (int k=0;k<9;k++){
      int ek = (k<KNNK)? n*KNNK+k : NKE+n;
      u += bh[k]*aVe[ek*1792 + h*448 + p*32 + dd];
    }
    Xs[p][tid] = sspf(u);
  }
  __syncthreads();
  const float* WOt = wt + 3*16384;
  float acc[NCA];
  #pragma unroll
  for (int p=0;p<NCA;p++) acc[p]=0.f;
  for (int c=0;c<HCH;c++){
    float w = WOt[c*128+tid];
    #pragma unroll
    for (int p=0;p<NCA;p++) acc[p] += Xs[p][c]*w;
  }
  int cnt = ccount(res_S[n]);
  for (int p=0;p<NCA;p++){
    float am = (p<cnt)?1.f:0.f;
    float outv = (resHn[(n*NCA+p)*HCH+tid] + acc[p])*am;
    resH2[(n*NCA+p)*HCH+tid] = outv;
  }
  if (tid < NCA*3){
    int isbf = *flag;
    int p=tid/3, jx=tid%3;
    float s=0;
    #pragma unroll
    for (int k=0;k<9;k++){
      int ek=(k<KNNK)? n*KNNK+k : NKE+n;
      s += betam[k]*dXe[(ek*NCA+p)*3+jx];
    }
    float base = cvt[O_RESX+(n*NCA+p)*3+jx];
    float v = (inv_row[n]>=0) ? base + fminf(fmaxf(s,-3.f),3.f) : base;
    resX2[(n*NCA+p)*3+jx] = v;
    storeOut(d_out, isbf, OUTX_OFF + (n*NCA+p)*3+jx, v);
  }
}

// ------------------------------------------------- k6a: ligand-edge logits via sig1 table
__global__ __launch_bounds__(256) void k6a_logits(
    const float* __restrict__ cvt, const int* __restrict__ row1, const int* __restrict__ col1,
    const float* __restrict__ resX2, const float* __restrict__ Qw, const float* __restrict__ Klw,
    const float* __restrict__ sig1T, float* __restrict__ LG1w)
{
  __shared__ float Bq[1848];       // 14 rows, stride 132
  __shared__ float Bk[32*133];     // 32 rows, stride 133 (5q+dd banks all distinct)
  __shared__ float Xr[42], Lp[96];
  int e = blockIdx.x, tid = threadIdx.x;
  int rr = row1[e] & 255, cb = col1[e] & 3;
  for (int i=tid;i<NCA*HCH;i+=256){ int p=i>>7,c=i&127; Bq[p*132+c]=Qw[rr*1792+i]; }
  for (int i=tid;i<LC*HCH;i+=256){ int q=i>>7,c=i&127; Bk[q*133+c]=Klw[cb*LC*HCH+i]; }
  if (tid >= 8 && tid < 50){
    int i=tid-8; int p=i/3, jx=i%3;
    Xr[i] = resX2[(rr*NCA+p)*3+jx];
  }
  if (tid >= 64 && tid < 160){
    int i=tid-64; int q=i/3, jx=i%3;
    Lp[i] = cvt[O_LPOS+(cb*LC+q)*3+jx];
  }
  __syncthreads();

  for (int pair=tid; pair<NCA*LC; pair+=256){
    int p = pair>>5, q = pair&31;
    float dx=Xr[p*3]-Lp[q*3], dy=Xr[p*3+1]-Lp[q*3+1], dz=Xr[p*3+2]-Lp[q*3+2];
    float d = sqrtf(fmaxf(dx*dx+dy*dy+dz*dz,1e-12f));
    int i0 = (int)(fminf(d, DMAXT)*TSCALE + 0.5f);
    float4 sg = ((const float4*)sig1T)[i0];
    float q0=0,q1=0,q2=0,q3=0;
    #pragma unroll
    for (int dd=0;dd<DH;dd++){
      q0 += Bq[p*132+dd]   *Bk[q*133+dd];
      q1 += Bq[p*132+32+dd]*Bk[q*133+32+dd];
      q2 += Bq[p*132+64+dd]*Bk[q*133+64+dd];
      q3 += Bq[p*132+96+dd]*Bk[q*133+96+dd];
    }
    const float isq=0.17677669529663687f;
    LG1w[e*1792 + 0*448 + pair] = q0*isq+sg.x;
    LG1w[e*1792 + 1*448 + pair] = q1*isq+sg.y;
    LG1w[e*1792 + 2*448 + pair] = q2*isq+sg.z;
    LG1w[e*1792 + 3*448 + pair] = q3*isq+sg.w;
  }
}

// ------------------------------------------------- k6b: ligand-edge softmaxes + aVr + aVlg
__global__ __launch_bounds__(256) void k6b_att(
    const float* __restrict__ cvt, const int* __restrict__ res_S,
    const int* __restrict__ row1, const int* __restrict__ col1,
    const float* __restrict__ LG1w, const float* __restrict__ Vw, const float* __restrict__ Vlw,
    float* __restrict__ r1_ws, float* __restrict__ aVr, float* __restrict__ aVlg)
{
  __shared__ float LG[1792];
  __shared__ float ALs[1792];
  __shared__ float Vl[4224];
  __shared__ float Vr[1848];
  __shared__ float amr[14], lm[32], s2r[56], rpart[56], cnts[2];
  int e = blockIdx.x, tid = threadIdx.x;
  int rr = row1[e] & 255, cb = col1[e] & 3;

  for (int i=tid;i<1792;i+=256) LG[i] = LG1w[e*1792+i];
  for (int i=tid;i<LC*HCH;i+=256){ int q=i>>7, c=i&127; Vl[q*132+c] = Vlw[cb*LC*HCH + i]; }
  for (int i=tid;i<NCA*HCH;i+=256){ int p=i>>7, c=i&127; Vr[p*132+c] = Vw[rr*NCA*HCH + i]; }
  if (tid < NCA) amr[tid] = (tid < ccount(res_S[rr])) ? 1.f : 0.f;
  if (tid >= 32 && tid < 64) lm[tid-32] = cvt[O_LMASK + cb*LC + tid-32];
  __syncthreads();

  if (tid < 56){
    int h=tid/14, pp=tid%14;
    float ap=amr[pp];
    float s=0, m=-INFINITY;
    for (int qq=0;qq<LC;qq++){ float v=LG[h*448+pp*32+qq]; s+=v*lm[qq]; m=fmaxf(m,v); }
    rpart[h*14+pp]=s*ap;
    float sum=0;
    for (int qq=0;qq<LC;qq++) sum+=expf(LG[h*448+pp*32+qq]-m);
    float inv=1.f/sum, s2=0;
    for (int qq=0;qq<LC;qq++) s2 += expf(LG[h*448+pp*32+qq]-m)*inv*ap*lm[qq];
    s2r[h*14+pp] = s2/(s2+1e-7f);
  }
  if (tid==56){
    float sr=0,sl=0;
    for(int i=0;i<NCA;i++) sr+=amr[i];
    for(int i=0;i<LC;i++) sl+=lm[i];
    cnts[0]=sr; cnts[1]=sl;
  }
  __syncthreads();
  if (tid < NH){
    float s=0; for (int pp=0;pp<NCA;pp++) s+=rpart[tid*14+pp];
    r1_ws[e*NH+tid]=s/(cnts[0]*cnts[1]);
  }
  if (tid < NH*LC){
    int h=tid>>5, qq=tid&31;
    float m=-INFINITY;
    for (int pp=0;pp<NCA;pp++) m=fmaxf(m,LG[h*448+pp*32+qq]);
    float sum=0;
    for (int pp=0;pp<NCA;pp++) sum+=expf(LG[h*448+pp*32+qq]-m);
    float inv=1.f/sum;
    float lq=lm[qq];
    for (int pp=0;pp<NCA;pp++){
      float a=expf(LG[h*448+pp*32+qq]-m)*inv*amr[pp]*lq;
      ALs[h*448+pp*32+qq]=a/(s2r[h*14+pp]+1e-7f);
    }
  }
  __syncthreads();
  if (tid < 56){
    int h=tid/14, pp=tid%14;
    float ap=amr[pp];
    float m=-INFINITY;
    for (int qq=0;qq<LC;qq++) m=fmaxf(m,LG[h*448+pp*32+qq]);
    float row[LC];
    float sum=0;
    for (int qq=0;qq<LC;qq++){ row[qq]=expf(LG[h*448+pp*32+qq]-m); sum+=row[qq]; }
    float inv=1.f/sum, s2=0;
    for (int qq=0;qq<LC;qq++){ row[qq]=row[qq]*inv*ap*lm[qq]; s2+=row[qq]; }
    float inv2=1.f/(s2+1e-7f);
    for (int qq=0;qq<LC;qq++) LG[h*448+pp*32+qq]=row[qq]*inv2;
  }
  __syncthreads();
  for (int j=tid;j<NH*NCA*DH;j+=256){
    int h=j/448, rem=j%448, pp=rem>>5, dd=rem&31;
    float acc=0;
    #pragma unroll
    for (int qq=0;qq<LC;qq++) acc += LG[h*448+pp*32+qq]*Vl[qq*132+h*32+dd];
    aVr[e*1792+j]=acc;
  }
  for (int j=tid;j<NH*LC*DH;j+=256){
    int h=j>>10, rem=j&1023, qq=rem>>5, dd=rem&31;
    float acc=0;
    #pragma unroll
    for (int pp=0;pp<NCA;pp++) acc += ALs[h*448+pp*32+qq]*Vr[pp*132+h*32+dd];
    aVlg[e*4096+j]=acc;
  }
}

// ------------------------------------------------- k7: finalize res_H3
__global__ __launch_bounds__(128) void k7_finalH(
    const int* __restrict__ inv_row, const int* __restrict__ res_S,
    const float* __restrict__ resH2, const float* __restrict__ aVr,
    const float* __restrict__ wt, const int* __restrict__ flag, void* __restrict__ d_out)
{
  int n=blockIdx.x, tid=threadIdx.x;
  int e = inv_row[n];
  __shared__ float G[NCA][HCH];
  if (e>=0){
    for (int j=tid;j<NCA*HCH;j+=128){
      int h=j/448, rem=j%448, pp=rem>>5, dd=rem&31;
      G[pp][h*DH+dd] = sspf(aVr[e*1792+j]);
    }
  }
  __syncthreads();
  float acc[NCA];
  #pragma unroll
  for (int p=0;p<NCA;p++) acc[p]=0.f;
  if (e>=0){
    const float* WOlt = wt + 6*16384;
    for (int c=0;c<HCH;c++){
      float w=WOlt[c*128+tid];
      #pragma unroll
      for (int p=0;p<NCA;p++) acc[p]+=G[p][c]*w;
    }
  }
  int cnt=ccount(res_S[n]);
  int isbf = *flag;
  for (int p=0;p<NCA;p++){
    float am=(p<cnt)?1.f:0.f;
    float v=(resH2[(n*NCA+p)*HCH+tid]+acc[p])*am;
    storeOut(d_out, isbf, (n*NCA+p)*HCH+tid, v);
  }
}

// ------------------------------------------------- k8: beta1 + updL + WOl1 -> lf2
__global__ __launch_bounds__(128) void k8_lf2(
    const int* __restrict__ col1, const float* __restrict__ r1_ws, const float* __restrict__ aVlg,
    const float* __restrict__ lf, const float* __restrict__ wt, const int* __restrict__ flag,
    void* __restrict__ d_out)
{
  int rb=blockIdx.x, tid=threadIdx.x;
  int b=rb>>5, q=rb&31;
  __shared__ float bw[NE1][NH];
  __shared__ float xs[HCH];
  if (tid<NH){
    int h=tid;
    float m=-INFINITY;
    for (int e=0;e<NE1;e++) if ((col1[e]&3)==b) m=fmaxf(m, r1_ws[e*NH+h]);
    float s=0;
    for (int e=0;e<NE1;e++) if ((col1[e]&3)==b) s+=expf(r1_ws[e*NH+h]-m);
    for (int e=0;e<NE1;e++) bw[e][h] = ((col1[e]&3)==b)? expf(r1_ws[e*NH+h]-m)/s : 0.f;
  }
  __syncthreads();
  int h=tid>>5, dd=tid&31;
  float u=0;
  for (int e=0;e<NE1;e++) u += bw[e][h]*aVlg[e*4096 + h*1024 + q*32 + dd];
  xs[tid]=sspf(u);
  __syncthreads();
  const float* WOl1t = wt + 7*16384;
  float acc=0;
  for (int c=0;c<HCH;c++) acc += xs[c]*WOl1t[c*128+tid];
  float v = lf[rb*HCH+tid] + acc;
  storeOut(d_out, *flag, OUTL_OFF + rb*HCH+tid, v);
}

// ================================================================ launch
extern "C" void kernel_launch(void* const* d_in, const int* in_sizes, int n_in,
                              void* d_out, int out_size, void* d_ws, size_t ws_size,
                              hipStream_t stream)
{
  const int* res_S = (const int*)d_in[29];
  const int* batch = (const int*)d_in[30];
  const int* row1  = (const int*)d_in[32];
  const int* col1  = (const int*)d_in[33];

  float* wsf = (float*)d_ws;
  size_t o = 0;
  int*   flag    = (int*)(wsf + o); o += 4;
  float* cvt     = wsf + o; o += CVT_RSV;
  float* wt      = wsf + o; o += 10*16384;
  int*   inv_row = (int*)(wsf + o); o += 256;
  int*   nbr     = (int*)(wsf + o); o += NRES*KNNK;
  float* resHn   = wsf + o; o += NRES*NCA*HCH;
  float* Qw      = wsf + o; o += NRES*NCA*HCH;
  float* Kw      = wsf + o; o += NRES*NCA*HCH;
  float* Vw      = wsf + o; o += NRES*NCA*HCH;
  float* TQw     = wsf + o; o += NRES*NCA*HCH;
  float* TKw     = wsf + o; o += NRES*NCA*HCH;
  float* r_ws    = wsf + o; o += NEDGE*NH;
  float* aVe     = wsf + o; o += (size_t)NEDGE*1792;
  float* dXe     = wsf + o; o += NEDGE*NCA*3;
  float* resH2   = wsf + o; o += NRES*NCA*HCH;
  float* resX2   = wsf + o; o += NRES*NCA*3;
  float* lf      = wsf + o; o += 4*LC*HCH;
  float* Klw     = wsf + o; o += 4*LC*HCH;
  float* Vlw     = wsf + o; o += 4*LC*HCH;
  float* r1w     = wsf + o; o += NE1*NH;
  float* aVrw    = wsf + o; o += NE1*1792;
  float* aVlgw   = wsf + o; o += NE1*4096;
  float* LGw     = wsf + o; o += (size_t)NEDGE*784;
  float* FRw     = wsf + o; o += NEDGE*196;
  float* LG1w    = wsf + o; o += NE1*1792;
  float* cT      = wsf + o; o += (size_t)NT*128;
  float* sigT    = wsf + o; o += NT*4;
  float* sig1T   = wsf + o; o += NT*4;
  // total ~46.1 MB

  kdet<<<1, 64, 0, stream>>>((const unsigned*)d_in[0], flag);
  kcvt<<<(TOTCVT+255)/256, 256, 0, stream>>>(flag,
      d_in[0],d_in[1],d_in[2],d_in[3],d_in[4],d_in[5],d_in[6],d_in[7],d_in[8],
      d_in[9],d_in[10],d_in[11],d_in[12],d_in[13],d_in[14],d_in[15],d_in[16],
      d_in[17],d_in[18],d_in[19],d_in[20],d_in[21],d_in[22],d_in[23],d_in[24],
      d_in[25],d_in[26],d_in[27],d_in[28], cvt);
  ktab<<<NT, 128, 0, stream>>>(cvt, cT, sigT, sig1T);
  k0_prep<<<641, 256, 0, stream>>>(cvt, row1, wt, inv_row);
  k1_res_proj<<<NRES, 128, 0, stream>>>(cvt, wt, resHn, Qw, Kw, Vw, TQw, TKw);
  k2_knn<<<NRES, 256, 0, stream>>>(cvt, batch, nbr);
  k5_ligproj<<<4*LC, 128, 0, stream>>>(cvt, wt, lf, Klw, Vlw);
  k3a_logits<<<NEDGE, 256, 0, stream>>>(cvt, nbr, Qw, Kw, TQw, TKw, cT, sigT, LGw, FRw);
  k3b_att<<<NEDGE, 256, 0, stream>>>(cvt, res_S, nbr, LGw, FRw, Vw, r_ws, aVe, dXe);
  k4_agg<<<NRES, 128, 0, stream>>>(cvt, res_S, inv_row, r_ws, aVe, dXe, resHn, wt, flag,
                                   resH2, resX2, d_out);
  k6a_logits<<<NE1, 256, 0, stream>>>(cvt, row1, col1, resX2, Qw, Klw, sig1T, LG1w);
  k6b_att<<<NE1, 256, 0, stream>>>(cvt, res_S, row1, col1, LG1w, Vw, Vlw, r1w, aVrw, aVlgw);
  k7_finalH<<<NRES, 128, 0, stream>>>(inv_row, res_S, resH2, aVrw, wt, flag, d_out);
  k8_lf2<<<4*LC, 128, 0, stream>>>(col1, r1w, aVlgw, lf, wt, flag, d_out);
}

// Round 5
// 360.840 us; speedup vs baseline: 2.7150x; 1.0783x over previous
//
#include <hip/hip_runtime.h>
#include <hip/hip_bf16.h>
#include <math.h>

typedef __hip_bfloat16 bf16;

#define NRES 256
#define LC   32
#define HCH  128
#define ECH  64
#define NH   4
#define NCA  14
#define KNNK 8
#define DH   32
#define NKE  (NRES*KNNK)      // 2048
#define NEDGE (NKE+NRES)      // 2304
#define NE1  64
#define NROWS (NRES*NCA)      // 3584

// distance tables: nearest-neighbor, h=1/256, domain [0,12]
#define NT     3073
#define TSCALE 256.0f
#define DMAXT  12.0f

// ---- fp32 converted-input region offsets (floats) ----
#define O_RESH   0
#define O_RESX   458752
#define O_LPOS   469504
#define O_LFEAT  469888
#define O_LMASK  486272
#define O_LNG    486400
#define O_LNB    486528
#define O_LN1G   486656
#define O_LN1B   486784
#define O_WQ     486912
#define O_WK     503296
#define O_WV     519680
#define O_WKL    536064
#define O_WVL    552448
#define O_WO     568832
#define O_WOL    585216
#define O_WOL1   601600
#define O_TIW1   617984
#define O_TIB1   658944
#define O_TIW2   659072
#define O_TIB2   659200
#define O_SDW1   659204
#define O_SDB1   667396
#define O_SDW2   667524
#define O_SDB2   668036
#define O_SD1W1  668040
#define O_SD1B1  676232
#define O_SD1W2  676360
#define O_SD1B2  676872
#define TOTCVT   676876
#define CVT_RSV  676880

#define OUTX_OFF 458752
#define OUTL_OFF 469504

__constant__ int c_counts[21] = {14,5,11,8,8,6,9,9,4,10,8,8,9,8,11,7,6,7,14,12,7};

__device__ __forceinline__ float b2f(bf16 x){ return __bfloat162float(x); }
__device__ __forceinline__ float sspf(float x){
  return fmaxf(x,0.f) + log1pf(expf(-fabsf(x))) - 0.6931471805599453f;
}
__device__ __forceinline__ int ccount(int s){ return c_counts[s<0?0:(s>20?20:s)]; }
__device__ __forceinline__ void storeOut(void* out, int isbf, int idx, float v){
  if (isbf) ((bf16*)out)[idx] = __float2bfloat16(v);
  else      ((float*)out)[idx] = v;
}

// ---------------------------------------------------------------- kdet: detect input float dtype
__global__ __launch_bounds__(64) void kdet(const unsigned* __restrict__ resH_raw, int* __restrict__ flag)
{
  int tid = threadIdx.x;
  unsigned w = resH_raw[tid];
  unsigned lo = w & 0xFFFFu;
  int e = (lo >> 7) & 0xFF;
  int good = (lo == 0u) || (e >= 121 && e <= 133);
  unsigned long long m = __ballot(good);
  if (tid == 0) flag[0] = (__popcll(m) >= 40) ? 1 : 0;   // 1 = inputs are bf16
}

// ---------------------------------------------------------------- kcvt: all float inputs -> fp32 copies
__global__ __launch_bounds__(256) void kcvt(
    const int* __restrict__ flag,
    const void* s0,const void* s1,const void* s2,const void* s3,const void* s4,
    const void* s5,const void* s6,const void* s7,const void* s8,const void* s9,
    const void* s10,const void* s11,const void* s12,const void* s13,const void* s14,
    const void* s15,const void* s16,const void* s17,const void* s18,const void* s19,
    const void* s20,const void* s21,const void* s22,const void* s23,const void* s24,
    const void* s25,const void* s26,const void* s27,const void* s28,
    float* __restrict__ dst)
{
  int g = blockIdx.x*256 + threadIdx.x;
  if (g >= TOTCVT) return;
  const void* src; int l;
  if      (g < O_RESX ) { src=s0;  l=g; }
  else if (g < O_LPOS ) { src=s1;  l=g-O_RESX; }
  else if (g < O_LFEAT) { src=s2;  l=g-O_LPOS; }
  else if (g < O_LMASK) { src=s3;  l=g-O_LFEAT; }
  else if (g < O_LNG  ) { src=s4;  l=g-O_LMASK; }
  else if (g < O_LNB  ) { src=s5;  l=g-O_LNG; }
  else if (g < O_LN1G ) { src=s6;  l=g-O_LNB; }
  else if (g < O_LN1B ) { src=s7;  l=g-O_LN1G; }
  else if (g < O_WQ   ) { src=s8;  l=g-O_LN1B; }
  else if (g < O_WK   ) { src=s9;  l=g-O_WQ; }
  else if (g < O_WV   ) { src=s10; l=g-O_WK; }
  else if (g < O_WKL  ) { src=s11; l=g-O_WV; }
  else if (g < O_WVL  ) { src=s12; l=g-O_WKL; }
  else if (g < O_WO   ) { src=s13; l=g-O_WVL; }
  else if (g < O_WOL  ) { src=s14; l=g-O_WO; }
  else if (g < O_WOL1 ) { src=s15; l=g-O_WOL; }
  else if (g < O_TIW1 ) { src=s16; l=g-O_WOL1; }
  else if (g < O_TIB1 ) { src=s17; l=g-O_TIW1; }
  else if (g < O_TIW2 ) { src=s18; l=g-O_TIB1; }
  else if (g < O_TIB2 ) { src=s19; l=g-O_TIW2; }
  else if (g < O_SDW1 ) { src=s20; l=0; }
  else if (g < O_SDB1 ) { src=s21; l=g-O_SDW1; }
  else if (g < O_SDW2 ) { src=s22; l=g-O_SDB1; }
  else if (g < O_SDB2 ) { src=s23; l=g-O_SDW2; }
  else if (g < O_SD1W1) { src=s24; l=g-O_SDB2; }
  else if (g < O_SD1B1) { src=s25; l=g-O_SD1W1; }
  else if (g < O_SD1W2) { src=s26; l=g-O_SD1B1; }
  else if (g < O_SD1B2) { src=s27; l=g-O_SD1W2; }
  else                  { src=s28; l=g-O_SD1B2; }
  float v = (*flag) ? b2f(((const bf16*)src)[l]) : ((const float*)src)[l];
  dst[g] = v;
}

// ---------------------------------------------------------------- ktab: distance-function tables
__global__ __launch_bounds__(128) void ktab(const float* __restrict__ cvt,
    float* __restrict__ cT, float* __restrict__ sigT, float* __restrict__ sig1T)
{
  int i = blockIdx.x, o = threadIdx.x;
  __shared__ float dr[64];
  __shared__ float W[128*65];
  __shared__ float h1[128], h1b[128];
  float d = (float)i * (1.0f/256.0f);
  const float step = 10.0f/63.0f;
  const float coef = -0.5f/(step*step);
  if (o < 64){ float t = d - step*(float)o; dr[o] = expf(coef*t*t); }
  for (int idx=o; idx<8192; idx+=128){ int oo=idx>>6, k=idx&63; W[oo*65+k] = cvt[O_TIW1 + oo*320 + 256 + k]; }
  __syncthreads();
  {
    float c = cvt[O_TIB1+o];
    for (int k=0;k<64;k++) c += dr[k]*W[o*65+k];
    cT[i*128+o] = c;
  }
  __syncthreads();
  for (int idx=o; idx<8192; idx+=128){ int oo=idx>>6, k=idx&63; W[oo*65+k] = cvt[O_SDW1 + idx]; }
  __syncthreads();
  {
    float a = cvt[O_SDB1+o];
    for (int k=0;k<64;k++) a += dr[k]*W[o*65+k];
    h1[o] = fmaxf(a,0.f);
  }
  __syncthreads();
  for (int idx=o; idx<8192; idx+=128){ int oo=idx>>6, k=idx&63; W[oo*65+k] = cvt[O_SD1W1 + idx]; }
  __syncthreads();
  {
    float a2 = cvt[O_SD1B1+o];
    for (int k=0;k<64;k++) a2 += dr[k]*W[o*65+k];
    h1b[o] = fmaxf(a2,0.f);
  }
  __syncthreads();
  if (o < 8){
    int h = o & 3;
    const float* hh = (o<4)? h1 : h1b;
    int wbase = (o<4)? O_SDW2 : O_SD1W2;
    int bbase = (o<4)? O_SDB2 : O_SD1B2;
    float s = cvt[bbase + h];
    for (int k=0;k<128;k++) s += hh[k]*cvt[wbase + h*128 + k];
    if (o<4) sigT[i*4+h] = s; else sig1T[i*4+h] = s;
  }
}

// ---------------------------------------------------------------- k0: transpose weights + inv_row
__global__ __launch_bounds__(256) void k0_prep(
    const float* __restrict__ cvt, const int* __restrict__ row1,
    float* __restrict__ wt, int* __restrict__ inv_row)
{
  int bid = blockIdx.x, tid = threadIdx.x;
  if (bid == 640){
    if (tid < NRES) inv_row[tid] = -1;
    __syncthreads();
    if (tid < NE1) inv_row[row1[tid] & 255] = tid;
    return;
  }
  int gid = bid*256 + tid;
  int m = gid >> 14;
  int j = gid & 16383;
  int o = j >> 7, c = j & 127;
  float v;
  switch(m){
    case 0: v = cvt[O_WQ  + j]; break;
    case 1: v = cvt[O_WK  + j]; break;
    case 2: v = cvt[O_WV  + j]; break;
    case 3: v = cvt[O_WO  + j]; break;
    case 4: v = cvt[O_WKL + j]; break;
    case 5: v = cvt[O_WVL + j]; break;
    case 6: v = cvt[O_WOL + j]; break;
    case 7: v = cvt[O_WOL1+ j]; break;
    case 8: v = cvt[O_TIW1 + o*320 + c]; break;
    default:v = cvt[O_TIW1 + o*320 + 128 + c]; break;
  }
  wt[m*16384 + c*128 + o] = v;
}

// ------------------------------------------------- kLN: per-row LayerNorm (one wave per row)
__global__ __launch_bounds__(256) void kLN(const float* __restrict__ cvt, float* __restrict__ resHn)
{
  int tid = threadIdx.x;
  int r = blockIdx.x*4 + (tid>>6);          // 3584 rows, 4 per block (one per wave)
  int lane = tid & 63;
  const float* x = cvt + O_RESH + r*HCH;
  float v0 = x[lane], v1 = x[lane+64];
  float s = v0 + v1;
  #pragma unroll
  for (int off=1; off<64; off<<=1) s += __shfl_xor(s, off);
  float mu = s*(1.f/HCH);
  float d0 = v0-mu, d1 = v1-mu;
  float q = d0*d0 + d1*d1;
  #pragma unroll
  for (int off=1; off<64; off<<=1) q += __shfl_xor(q, off);
  float inv = rsqrtf(q*(1.f/HCH) + 1e-5f);
  resHn[r*HCH + lane]      = d0*inv*cvt[O_LNG+lane]    + cvt[O_LNB+lane];
  resHn[r*HCH + lane + 64] = d1*inv*cvt[O_LNG+lane+64] + cvt[O_LNB+lane+64];
}

// ------------------------------------------------- kQKV: [3584,128] @ Wt -> Q/K/V (tiled GEMM)
// grid (224, 3); block 256; thread tile 2 rows x 4 cols; Xs stride 129 (conflict-free)
__global__ __launch_bounds__(256) void kQKV(
    const float* __restrict__ resHn, const float* __restrict__ wt,
    float* __restrict__ Qw, float* __restrict__ Kw, float* __restrict__ Vw)
{
  int m = blockIdx.y;
  int rt = blockIdx.x * 16;
  int tid = threadIdx.x;
  int tc = (tid & 31) * 4;
  int tr = (tid >> 5) * 2;
  __shared__ float Xs[16*129];
  for (int i=tid; i<16*128; i+=256){
    int r = i>>7, c = i&127;
    Xs[r*129 + c] = resHn[(rt+r)*HCH + c];
  }
  __syncthreads();
  const float* W = wt + m*16384;
  float a00=0,a01=0,a02=0,a03=0, a10=0,a11=0,a12=0,a13=0;
  for (int c=0;c<HCH;c++){
    float4 w4 = *(const float4*)(W + c*128 + tc);
    float x0 = Xs[tr*129 + c];
    float x1 = Xs[(tr+1)*129 + c];
    a00 += x0*w4.x; a01 += x0*w4.y; a02 += x0*w4.z; a03 += x0*w4.w;
    a10 += x1*w4.x; a11 += x1*w4.y; a12 += x1*w4.z; a13 += x1*w4.w;
  }
  float* out = (m==0)? Qw : (m==1)? Kw : Vw;
  *(float4*)(out + (rt+tr  )*HCH + tc) = make_float4(a00,a01,a02,a03);
  *(float4*)(out + (rt+tr+1)*HCH + tc) = make_float4(a10,a11,a12,a13);
}

// ------------------------------------------------- kTQTK: TQ = Q@TiQt, TK = K@TiKt
__global__ __launch_bounds__(256) void kTQTK(
    const float* __restrict__ Qw, const float* __restrict__ Kw, const float* __restrict__ wt,
    float* __restrict__ TQw, float* __restrict__ TKw)
{
  int m = blockIdx.y;
  int rt = blockIdx.x * 16;
  int tid = threadIdx.x;
  int tc = (tid & 31) * 4;
  int tr = (tid >> 5) * 2;
  __shared__ float Xs[16*129];
  const float* in = m ? Kw : Qw;
  for (int i=tid; i<16*128; i+=256){
    int r = i>>7, c = i&127;
    Xs[r*129 + c] = in[(rt+r)*HCH + c];
  }
  __syncthreads();
  const float* W = wt + (8+m)*16384;
  float a00=0,a01=0,a02=0,a03=0, a10=0,a11=0,a12=0,a13=0;
  for (int c=0;c<HCH;c++){
    float4 w4 = *(const float4*)(W + c*128 + tc);
    float x0 = Xs[tr*129 + c];
    float x1 = Xs[(tr+1)*129 + c];
    a00 += x0*w4.x; a01 += x0*w4.y; a02 += x0*w4.z; a03 += x0*w4.w;
    a10 += x1*w4.x; a11 += x1*w4.y; a12 += x1*w4.z; a13 += x1*w4.w;
  }
  float* out = m ? TKw : TQw;
  *(float4*)(out + (rt+tr  )*HCH + tc) = make_float4(a00,a01,a02,a03);
  *(float4*)(out + (rt+tr+1)*HCH + tc) = make_float4(a10,a11,a12,a13);
}

// ------------------------------------------------- k2: KNN (replicates lax.top_k tie-break)
__global__ __launch_bounds__(256) void k2_knn(
    const float* __restrict__ cvt, const int* __restrict__ batch, int* __restrict__ nbr)
{
  int n = blockIdx.x, j = threadIdx.x;
  __shared__ float sd[256];
  __shared__ float rd[256];
  __shared__ int   ri[256];
  float cx = cvt[O_RESX+(n*NCA+1)*3+0];
  float cy = cvt[O_RESX+(n*NCA+1)*3+1];
  float cz = cvt[O_RESX+(n*NCA+1)*3+2];
  float jx = cvt[O_RESX+(j*NCA+1)*3+0];
  float jy = cvt[O_RESX+(j*NCA+1)*3+1];
  float jz = cvt[O_RESX+(j*NCA+1)*3+2];
  float dx=cx-jx, dy=cy-jy, dz=cz-jz;
  float d2 = dx*dx+dy*dy+dz*dz;
  bool bad = (batch[j]!=batch[n]) || (j==n);
  sd[j] = bad ? INFINITY : d2;
  __syncthreads();
  for (int k=0;k<KNNK;k++){
    rd[j]=sd[j]; ri[j]=j;
    __syncthreads();
    for (int off=128; off>0; off>>=1){
      if (j<off){
        float da=rd[j], db=rd[j+off];
        int ia=ri[j], ib=ri[j+off];
        if (db<da || (db==da && ib<ia)){ rd[j]=db; ri[j]=ib; }
      }
      __syncthreads();
    }
    if (j==0){ nbr[n*KNNK+k]=ri[0]; sd[ri[0]] = INFINITY; }
    __syncthreads();
  }
}

// ------------------------------------------------- k5: ligand LN + Kl/Vl projections
__global__ __launch_bounds__(128) void k5_ligproj(
    const float* __restrict__ cvt, const float* __restrict__ wt, float* __restrict__ lf,
    float* __restrict__ Klw, float* __restrict__ Vlw)
{
  int rb = blockIdx.x, tid = threadIdx.x;
  __shared__ float x[HCH];
  __shared__ float sred[2];
  float v = cvt[O_LFEAT + rb*HCH + tid];
  float s=v;
  for (int off=1; off<64; off<<=1) s += __shfl_xor(s, off);
  if ((tid&63)==0) sred[tid>>6]=s;
  __syncthreads();
  float mu=(sred[0]+sred[1])*(1.f/HCH);
  __syncthreads();
  float d=v-mu; s=d*d;
  for (int off=1; off<64; off<<=1) s += __shfl_xor(s, off);
  if ((tid&63)==0) sred[tid>>6]=s;
  __syncthreads();
  float var=(sred[0]+sred[1])*(1.f/HCH);
  float xh = d*rsqrtf(var+1e-5f)*cvt[O_LN1G+tid] + cvt[O_LN1B+tid];
  x[tid]=xh; lf[rb*HCH+tid]=xh;
  __syncthreads();
  const float* WKlt = wt + 4*16384;
  const float* WVlt = wt + 5*16384;
  float aK=0.f, aV=0.f;
  for (int c=0;c<HCH;c++){
    float xc=x[c];
    aK += xc*WKlt[c*128+tid];
    aV += xc*WVlt[c*128+tid];
  }
  Klw[rb*HCH+tid]=aK; Vlw[rb*HCH+tid]=aV;
}

// ------------------------------------------------- k3a: residue-edge logits via distance tables
__global__ __launch_bounds__(256) void k3a_logits(
    const float* __restrict__ cvt, const int* __restrict__ nbr,
    const float* __restrict__ Qw, const float* __restrict__ Kw,
    const float* __restrict__ TQw, const float* __restrict__ TKw,
    const float* __restrict__ cT, const float* __restrict__ sigT,
    float* __restrict__ LGw, float* __restrict__ FRw)
{
  __shared__ float Bq[1848], Bk[1848], Tq[1848], Tk[1848];   // stride 132
  __shared__ float tw2s[128], tb2s[1], Xr[42], Xc[42];
  int e = blockIdx.x, tid = threadIdx.x;
  int rr, cc;
  if (e < NKE){ rr = e >> 3; cc = nbr[e] & 255; } else { rr = e - NKE; cc = rr; }

  for (int i=tid;i<NCA*HCH;i+=256){
    int p=i>>7, c=i&127;
    Bq[p*132+c]=Qw[rr*1792+i];  Bk[p*132+c]=Kw[cc*1792+i];
    Tq[p*132+c]=TQw[rr*1792+i]; Tk[p*132+c]=TKw[cc*1792+i];
  }
  if (tid < 128) tw2s[tid]=cvt[O_TIW2+tid];
  if (tid == 128) tb2s[0]=cvt[O_TIB2];
  if (tid >= 136 && tid < 178){
    int i=tid-136; int p=i/3, jx=i%3;
    Xr[i] = cvt[O_RESX+(rr*NCA+p)*3+jx];
    Xc[i] = cvt[O_RESX+(cc*NCA+p)*3+jx];
  }
  __syncthreads();

  if (tid < 196){
    int p = tid/14, q = tid%14;
    float dx=Xr[p*3]-Xc[q*3], dy=Xr[p*3+1]-Xc[q*3+1], dz=Xr[p*3+2]-Xc[q*3+2];
    float d = sqrtf(fmaxf(dx*dx+dy*dy+dz*dz, 1e-12f));
    int i0 = (int)(fminf(d, DMAXT)*TSCALE + 0.5f);
    float4 sg = ((const float4*)sigT)[i0];
    const float4* crow = (const float4*)(cT + i0*128);
    float fa = tb2s[0];
    #pragma unroll 8
    for (int j=0;j<32;j++){
      float4 cb = crow[j];
      int o = 4*j;
      fa += fmaxf(Tq[p*132+o  ]+Tk[q*132+o  ]+cb.x, 0.f)*tw2s[o  ];
      fa += fmaxf(Tq[p*132+o+1]+Tk[q*132+o+1]+cb.y, 0.f)*tw2s[o+1];
      fa += fmaxf(Tq[p*132+o+2]+Tk[q*132+o+2]+cb.z, 0.f)*tw2s[o+2];
      fa += fmaxf(Tq[p*132+o+3]+Tk[q*132+o+3]+cb.w, 0.f)*tw2s[o+3];
    }
    float qk0=0,qk1=0,qk2=0,qk3=0;
    #pragma unroll
    for (int dd=0;dd<DH;dd++){
      qk0 += Bq[p*132+dd]   *Bk[q*132+dd];
      qk1 += Bq[p*132+32+dd]*Bk[q*132+32+dd];
      qk2 += Bq[p*132+64+dd]*Bk[q*132+64+dd];
      qk3 += Bq[p*132+96+dd]*Bk[q*132+96+dd];
    }
    const float isq = 0.17677669529663687f;   // 1/sqrt(32)
    LGw[e*784 + 0*196 + tid] = qk0*isq + sg.x;
    LGw[e*784 + 1*196 + tid] = qk1*isq + sg.y;
    LGw[e*784 + 2*196 + tid] = qk2*isq + sg.z;
    LGw[e*784 + 3*196 + tid] = qk3*isq + sg.w;
    FRw[e*196 + tid] = fa;
  }
}

// ------------------------------------------------- k3b: residue-edge softmax / r / aV / dX
__global__ __launch_bounds__(256) void k3b_att(
    const float* __restrict__ cvt, const int* __restrict__ res_S, const int* __restrict__ nbr,
    const float* __restrict__ LGw, const float* __restrict__ FRw, const float* __restrict__ Vw,
    float* __restrict__ r_ws, float* __restrict__ aVe, float* __restrict__ dXe)
{
  __shared__ float LG[784];
  __shared__ float FR[196];
  __shared__ float Vc[1848];
  __shared__ float Xr[42], Xc[42], amr[14], amc[14], rpart[56], cnts[2];
  int e = blockIdx.x, tid = threadIdx.x;
  int rr, cc;
  if (e < NKE){ rr = e >> 3; cc = nbr[e] & 255; } else { rr = e - NKE; cc = rr; }

  for (int i=tid;i<784;i+=256) LG[i] = LGw[e*784+i];
  if (tid < 196) FR[tid] = FRw[e*196+tid];
  for (int i=tid;i<NCA*HCH;i+=256){
    int p=i>>7, c=i&127;
    Vc[p*132+c] = Vw[cc*NCA*HCH + i];
  }
  if (tid >= 196 && tid < 196+42){
    int i=tid-196; int p=i/3, jx=i%3;
    Xr[i] = cvt[O_RESX+(rr*NCA+p)*3+jx];
    Xc[i] = cvt[O_RESX+(cc*NCA+p)*3+jx];
  }
  if (tid >= 242 && tid < 242+NCA){
    int p=tid-242;
    amr[p] = (p < ccount(res_S[rr])) ? 1.f : 0.f;
    amc[p] = (p < ccount(res_S[cc])) ? 1.f : 0.f;
  }
  __syncthreads();

  if (tid < 56){
    int h=tid/14, pp=tid%14;
    float ap = amr[pp];
    float row[NCA];
    float s=0;
    #pragma unroll
    for (int qq=0;qq<NCA;qq++){ row[qq]=LG[h*196+pp*14+qq]; s += row[qq]*amc[qq]; }
    rpart[h*14+pp] = s*ap;
    float m=-INFINITY;
    #pragma unroll
    for (int qq=0;qq<NCA;qq++) m=fmaxf(m,row[qq]);
    float sum=0;
    #pragma unroll
    for (int qq=0;qq<NCA;qq++){ row[qq]=expf(row[qq]-m); sum+=row[qq]; }
    float inv=1.f/sum, s2=0;
    #pragma unroll
    for (int qq=0;qq<NCA;qq++){ row[qq]=row[qq]*inv*ap*amc[qq]; s2+=row[qq]; }
    float inv2=1.f/(s2+1e-7f);
    #pragma unroll
    for (int qq=0;qq<NCA;qq++) LG[h*196+pp*14+qq]=row[qq]*inv2;
  }
  if (tid == 56){
    float sr=0, sc=0;
    for (int i=0;i<NCA;i++){ sr+=amr[i]; sc+=amc[i]; }
    cnts[0]=sr; cnts[1]=sc;
  }
  __syncthreads();
  if (tid < NH){
    float s=0;
    for (int pp=0;pp<NCA;pp++) s += rpart[tid*14+pp];
    r_ws[e*NH+tid] = s/(cnts[0]*cnts[1]);
  }
  if (tid < 196){
    int p=tid/14, q=tid%14;
    float ma = 0.25f*(LG[p*14+q] + LG[196+p*14+q] + LG[392+p*14+q] + LG[588+p*14+q]);
    FR[tid] *= ma;
  }
  __syncthreads();
  if (tid < NCA){
    int pp=tid;
    float ax=0, ay=0, az=0;
    #pragma unroll
    for (int qq=0;qq<NCA;qq++){
      float dx=Xr[pp*3]-Xc[qq*3], dy=Xr[pp*3+1]-Xc[qq*3+1], dz=Xr[pp*3+2]-Xc[qq*3+2];
      float nrm = sqrtf(fmaxf(dx*dx+dy*dy+dz*dz,1e-12f));
      float sc = FR[pp*14+qq]/(nrm+1e-5f);
      ax += sc*dx; ay += sc*dy; az += sc*dz;
    }
    dXe[(e*NCA+pp)*3+0]=ax; dXe[(e*NCA+pp)*3+1]=ay; dXe[(e*NCA+pp)*3+2]=az;
  }
  #pragma unroll
  for (int rep=0;rep<7;rep++){
    int jdx = rep*256 + tid;
    int h = jdx/448, rem = jdx%448;
    int pp = rem>>5, dd = rem&31;
    float acc=0;
    #pragma unroll
    for (int qq=0;qq<NCA;qq++) acc += LG[h*196+pp*14+qq]*Vc[qq*132 + h*32 + dd];
    aVe[e*1792 + jdx] = acc;
  }
}

// ------------------------------------------------- k4: per-residue beta + updH + WO + dX
__global__ __launch_bounds__(128) void k4_agg(
    const float* __restrict__ cvt, const int* __restrict__ res_S, const int* __restrict__ inv_row,
    const float* __restrict__ r_ws, const float* __restrict__ aVe, const float* __restrict__ dXe,
    const float* __restrict__ resHn, const float* __restrict__ wt, const int* __restrict__ flag,
    float* __restrict__ resH2, float* __restrict__ resX2, void* __restrict__ d_out)
{
  int n = blockIdx.x, tid = threadIdx.x;
  __shared__ float beta[9][NH];
  __shared__ float betam[9];
  __shared__ float Xs[NCA][HCH];
  if (tid < NH){
    int h = tid;
    float rv[9], m=-INFINITY;
    #pragma unroll
    for (int k=0;k<9;k++){
      int ek = (k<KNNK)? n*KNNK+k : NKE+n;
      rv[k] = r_ws[ek*NH+h];
      m = fmaxf(m, rv[k]);
    }
    float s=0;
    #pragma unroll
    for (int k=0;k<9;k++){ rv[k]=expf(rv[k]-m); s+=rv[k]; }
    #pragma unroll
    for (int k=0;k<9;k++) beta[k][h]=rv[k]/s;
  }
  __syncthreads();
  if (tid < 9) betam[tid] = 0.25f*(beta[tid][0]+beta[tid][1]+beta[tid][2]+beta[tid][3]);
  int h = tid>>5, dd = tid&31;
  float bh[9];
  #pragma unroll
  for (int k=0;k<9;k++) bh[k]=beta[k][h];
  for (int p=0;p<NCA;p++){
    float u=0;
    #pragma unroll
    for (int k=0;k<9;k++){
      int ek = (k<KNNK)? n*KNNK+k : NKE+n;
      u += bh[k]*aVe[ek*1792 + h*448 + p*32 + dd];
    }
    Xs[p][tid] = sspf(u);
  }
  __syncthreads();
  const float* WOt = wt + 3*16384;
  float acc[NCA];
  #pragma unroll
  for (int p=0;p<NCA;p++) acc[p]=0.f;
  for (int c=0;c<HCH;c++){
    float w = WOt[c*128+tid];
    #pragma unroll
    for (int p=0;p<NCA;p++) acc[p] += Xs[p][c]*w;
  }
  int cnt = ccount(res_S[n]);
  for (int p=0;p<NCA;p++){
    float am = (p<cnt)?1.f:0.f;
    float outv = (resHn[(n*NCA+p)*HCH+tid] + acc[p])*am;
    resH2[(n*NCA+p)*HCH+tid] = outv;
  }
  if (tid < NCA*3){
    int isbf = *flag;
    int p=tid/3, jx=tid%3;
    float s=0;
    #pragma unroll
    for (int k=0;k<9;k++){
      int ek=(k<KNNK)? n*KNNK+k : NKE+n;
      s += betam[k]*dXe[(ek*NCA+p)*3+jx];
    }
    float base = cvt[O_RESX+(n*NCA+p)*3+jx];
    float v = (inv_row[n]>=0) ? base + fminf(fmaxf(s,-3.f),3.f) : base;
    resX2[(n*NCA+p)*3+jx] = v;
    storeOut(d_out, isbf, OUTX_OFF + (n*NCA+p)*3+jx, v);
  }
}

// ------------------------------------------------- k6a: ligand-edge logits via sig1 table
__global__ __launch_bounds__(256) void k6a_logits(
    const float* __restrict__ cvt, const int* __restrict__ row1, const int* __restrict__ col1,
    const float* __restrict__ resX2, const float* __restrict__ Qw, const float* __restrict__ Klw,
    const float* __restrict__ sig1T, float* __restrict__ LG1w)
{
  __shared__ float Bq[1848];       // 14 rows, stride 132
  __shared__ float Bk[32*133];     // 32 rows, stride 133
  __shared__ float Xr[42], Lp[96];
  int e = blockIdx.x, tid = threadIdx.x;
  int rr = row1[e] & 255, cb = col1[e] & 3;
  for (int i=tid;i<NCA*HCH;i+=256){ int p=i>>7,c=i&127; Bq[p*132+c]=Qw[rr*1792+i]; }
  for (int i=tid;i<LC*HCH;i+=256){ int q=i>>7,c=i&127; Bk[q*133+c]=Klw[cb*LC*HCH+i]; }
  if (tid >= 8 && tid < 50){
    int i=tid-8; int p=i/3, jx=i%3;
    Xr[i] = resX2[(rr*NCA+p)*3+jx];
  }
  if (tid >= 64 && tid < 160){
    int i=tid-64; int q=i/3, jx=i%3;
    Lp[i] = cvt[O_LPOS+(cb*LC+q)*3+jx];
  }
  __syncthreads();

  for (int pair=tid; pair<NCA*LC; pair+=256){
    int p = pair>>5, q = pair&31;
    float dx=Xr[p*3]-Lp[q*3], dy=Xr[p*3+1]-Lp[q*3+1], dz=Xr[p*3+2]-Lp[q*3+2];
    float d = sqrtf(fmaxf(dx*dx+dy*dy+dz*dz,1e-12f));
    int i0 = (int)(fminf(d, DMAXT)*TSCALE + 0.5f);
    float4 sg = ((const float4*)sig1T)[i0];
    float q0=0,q1=0,q2=0,q3=0;
    #pragma unroll
    for (int dd=0;dd<DH;dd++){
      q0 += Bq[p*132+dd]   *Bk[q*133+dd];
      q1 += Bq[p*132+32+dd]*Bk[q*133+32+dd];
      q2 += Bq[p*132+64+dd]*Bk[q*133+64+dd];
      q3 += Bq[p*132+96+dd]*Bk[q*133+96+dd];
    }
    const float isq=0.17677669529663687f;
    LG1w[e*1792 + 0*448 + pair] = q0*isq+sg.x;
    LG1w[e*1792 + 1*448 + pair] = q1*isq+sg.y;
    LG1w[e*1792 + 2*448 + pair] = q2*isq+sg.z;
    LG1w[e*1792 + 3*448 + pair] = q3*isq+sg.w;
  }
}

// ------------------------------------------------- k6b: ligand-edge softmaxes + aVr + aVlg
__global__ __launch_bounds__(256) void k6b_att(
    const float* __restrict__ cvt, const int* __restrict__ res_S,
    const int* __restrict__ row1, const int* __restrict__ col1,
    const float* __restrict__ LG1w, const float* __restrict__ Vw, const float* __restrict__ Vlw,
    float* __restrict__ r1_ws, float* __restrict__ aVr, float* __restrict__ aVlg)
{
  __shared__ float LG[1792];
  __shared__ float ALs[1792];
  __shared__ float Vl[4224];
  __shared__ float Vr[1848];
  __shared__ float amr[14], lm[32], s2r[56], rpart[56], cnts[2];
  int e = blockIdx.x, tid = threadIdx.x;
  int rr = row1[e] & 255, cb = col1[e] & 3;

  for (int i=tid;i<1792;i+=256) LG[i] = LG1w[e*1792+i];
  for (int i=tid;i<LC*HCH;i+=256){ int q=i>>7, c=i&127; Vl[q*132+c] = Vlw[cb*LC*HCH + i]; }
  for (int i=tid;i<NCA*HCH;i+=256){ int p=i>>7, c=i&127; Vr[p*132+c] = Vw[rr*NCA*HCH + i]; }
  if (tid < NCA) amr[tid] = (tid < ccount(res_S[rr])) ? 1.f : 0.f;
  if (tid >= 32 && tid < 64) lm[tid-32] = cvt[O_LMASK + cb*LC + tid-32];
  __syncthreads();

  if (tid < 56){
    int h=tid/14, pp=tid%14;
    float ap=amr[pp];
    float s=0, m=-INFINITY;
    for (int qq=0;qq<LC;qq++){ float v=LG[h*448+pp*32+qq]; s+=v*lm[qq]; m=fmaxf(m,v); }
    rpart[h*14+pp]=s*ap;
    float sum=0;
    for (int qq=0;qq<LC;qq++) sum+=expf(LG[h*448+pp*32+qq]-m);
    float inv=1.f/sum, s2=0;
    for (int qq=0;qq<LC;qq++) s2 += expf(LG[h*448+pp*32+qq]-m)*inv*ap*lm[qq];
    s2r[h*14+pp] = s2/(s2+1e-7f);
  }
  if (tid==56){
    float sr=0,sl=0;
    for(int i=0;i<NCA;i++) sr+=amr[i];
    for(int i=0;i<LC;i++) sl+=lm[i];
    cnts[0]=sr; cnts[1]=sl;
  }
  __syncthreads();
  if (tid < NH){
    float s=0; for (int pp=0;pp<NCA;pp++) s+=rpart[tid*14+pp];
    r1_ws[e*NH+tid]=s/(cnts[0]*cnts[1]);
  }
  if (tid < NH*LC){
    int h=tid>>5, qq=tid&31;
    float m=-INFINITY;
    for (int pp=0;pp<NCA;pp++) m=fmaxf(m,LG[h*448+pp*32+qq]);
    float sum=0;
    for (int pp=0;pp<NCA;pp++) sum+=expf(LG[h*448+pp*32+qq]-m);
    float inv=1.f/sum;
    float lq=lm[qq];
    for (int pp=0;pp<NCA;pp++){
      float a=expf(LG[h*448+pp*32+qq]-m)*inv*amr[pp]*lq;
      ALs[h*448+pp*32+qq]=a/(s2r[h*14+pp]+1e-7f);
    }
  }
  __syncthreads();
  if (tid < 56){
    int h=tid/14, pp=tid%14;
    float ap=amr[pp];
    float m=-INFINITY;
    for (int qq=0;qq<LC;qq++) m=fmaxf(m,LG[h*448+pp*32+qq]);
    float row[LC];
    float sum=0;
    for (int qq=0;qq<LC;qq++){ row[qq]=expf(LG[h*448+pp*32+qq]-m); sum+=row[qq]; }
    float inv=1.f/sum, s2=0;
    for (int qq=0;qq<LC;qq++){ row[qq]=row[qq]*inv*ap*lm[qq]; s2+=row[qq]; }
    float inv2=1.f/(s2+1e-7f);
    for (int qq=0;qq<LC;qq++) LG[h*448+pp*32+qq]=row[qq]*inv2;
  }
  __syncthreads();
  for (int j=tid;j<NH*NCA*DH;j+=256){
    int h=j/448, rem=j%448, pp=rem>>5, dd=rem&31;
    float acc=0;
    #pragma unroll
    for (int qq=0;qq<LC;qq++) acc += LG[h*448+pp*32+qq]*Vl[qq*132+h*32+dd];
    aVr[e*1792+j]=acc;
  }
  for (int j=tid;j<NH*LC*DH;j+=256){
    int h=j>>10, rem=j&1023, qq=rem>>5, dd=rem&31;
    float acc=0;
    #pragma unroll
    for (int pp=0;pp<NCA;pp++) acc += ALs[h*448+pp*32+qq]*Vr[pp*132+h*32+dd];
    aVlg[e*4096+j]=acc;
  }
}

// ------------------------------------------------- k7: finalize res_H3
__global__ __launch_bounds__(128) void k7_finalH(
    const int* __restrict__ inv_row, const int* __restrict__ res_S,
    const float* __restrict__ resH2, const float* __restrict__ aVr,
    const float* __restrict__ wt, const int* __restrict__ flag, void* __restrict__ d_out)
{
  int n=blockIdx.x, tid=threadIdx.x;
  int e = inv_row[n];
  __shared__ float G[NCA][HCH];
  if (e>=0){
    for (int j=tid;j<NCA*HCH;j+=128){
      int h=j/448, rem=j%448, pp=rem>>5, dd=rem&31;
      G[pp][h*DH+dd] = sspf(aVr[e*1792+j]);
    }
  }
  __syncthreads();
  float acc[NCA];
  #pragma unroll
  for (int p=0;p<NCA;p++) acc[p]=0.f;
  if (e>=0){
    const float* WOlt = wt + 6*16384;
    for (int c=0;c<HCH;c++){
      float w=WOlt[c*128+tid];
      #pragma unroll
      for (int p=0;p<NCA;p++) acc[p]+=G[p][c]*w;
    }
  }
  int cnt=ccount(res_S[n]);
  int isbf = *flag;
  for (int p=0;p<NCA;p++){
    float am=(p<cnt)?1.f:0.f;
    float v=(resH2[(n*NCA+p)*HCH+tid]+acc[p])*am;
    storeOut(d_out, isbf, (n*NCA+p)*HCH+tid, v);
  }
}

// ------------------------------------------------- k8: beta1 + updL + WOl1 -> lf2
__global__ __launch_bounds__(128) void k8_lf2(
    const int* __restrict__ col1, const float* __restrict__ r1_ws, const float* __restrict__ aVlg,
    const float* __restrict__ lf, const float* __restrict__ wt, const int* __restrict__ flag,
    void* __restrict__ d_out)
{
  int rb=blockIdx.x, tid=threadIdx.x;
  int b=rb>>5, q=rb&31;
  __shared__ float bw[NE1][NH];
  __shared__ float xs[HCH];
  if (tid<NH){
    int h=tid;
    float m=-INFINITY;
    for (int e=0;e<NE1;e++) if ((col1[e]&3)==b) m=fmaxf(m, r1_ws[e*NH+h]);
    float s=0;
    for (int e=0;e<NE1;e++) if ((col1[e]&3)==b) s+=expf(r1_ws[e*NH+h]-m);
    for (int e=0;e<NE1;e++) bw[e][h] = ((col1[e]&3)==b)? expf(r1_ws[e*NH+h]-m)/s : 0.f;
  }
  __syncthreads();
  int h=tid>>5, dd=tid&31;
  float u=0;
  for (int e=0;e<NE1;e++) u += bw[e][h]*aVlg[e*4096 + h*1024 + q*32 + dd];
  xs[tid]=sspf(u);
  __syncthreads();
  const float* WOl1t = wt + 7*16384;
  float acc=0;
  for (int c=0;c<HCH;c++) acc += xs[c]*WOl1t[c*128+tid];
  float v = lf[rb*HCH+tid] + acc;
  storeOut(d_out, *flag, OUTL_OFF + rb*HCH+tid, v);
}

// ================================================================ launch
extern "C" void kernel_launch(void* const* d_in, const int* in_sizes, int n_in,
                              void* d_out, int out_size, void* d_ws, size_t ws_size,
                              hipStream_t stream)
{
  const int* res_S = (const int*)d_in[29];
  const int* batch = (const int*)d_in[30];
  const int* row1  = (const int*)d_in[32];
  const int* col1  = (const int*)d_in[33];

  float* wsf = (float*)d_ws;
  size_t o = 0;
  int*   flag    = (int*)(wsf + o); o += 4;
  float* cvt     = wsf + o; o += CVT_RSV;
  float* wt      = wsf + o; o += 10*16384;
  int*   inv_row = (int*)(wsf + o); o += 256;
  int*   nbr     = (int*)(wsf + o); o += NRES*KNNK;
  float* resHn   = wsf + o; o += NROWS*HCH;
  float* Qw      = wsf + o; o += NROWS*HCH;
  float* Kw      = wsf + o; o += NROWS*HCH;
  float* Vw      = wsf + o; o += NROWS*HCH;
  float* TQw     = wsf + o; o += NROWS*HCH;
  float* TKw     = wsf + o; o += NROWS*HCH;
  float* r_ws    = wsf + o; o += NEDGE*NH;
  float* aVe     = wsf + o; o += (size_t)NEDGE*1792;
  float* dXe     = wsf + o; o += NEDGE*NCA*3;
  float* resH2   = wsf + o; o += NROWS*HCH;
  float* resX2   = wsf + o; o += NRES*NCA*3;
  float* lf      = wsf + o; o += 4*LC*HCH;
  float* Klw     = wsf + o; o += 4*LC*HCH;
  float* Vlw     = wsf + o; o += 4*LC*HCH;
  float* r1w     = wsf + o; o += NE1*NH;
  float* aVrw    = wsf + o; o += NE1*1792;
  float* aVlgw   = wsf + o; o += NE1*4096;
  float* LGw     = wsf + o; o += (size_t)NEDGE*784;
  float* FRw     = wsf + o; o += NEDGE*196;
  float* LG1w    = wsf + o; o += NE1*1792;
  float* cT      = wsf + o; o += (size_t)NT*128;
  float* sigT    = wsf + o; o += NT*4;
  float* sig1T   = wsf + o; o += NT*4;

  kdet<<<1, 64, 0, stream>>>((const unsigned*)d_in[0], flag);
  kcvt<<<(TOTCVT+255)/256, 256, 0, stream>>>(flag,
      d_in[0],d_in[1],d_in[2],d_in[3],d_in[4],d_in[5],d_in[6],d_in[7],d_in[8],
      d_in[9],d_in[10],d_in[11],d_in[12],d_in[13],d_in[14],d_in[15],d_in[16],
      d_in[17],d_in[18],d_in[19],d_in[20],d_in[21],d_in[22],d_in[23],d_in[24],
      d_in[25],d_in[26],d_in[27],d_in[28], cvt);
  ktab<<<NT, 128, 0, stream>>>(cvt, cT, sigT, sig1T);
  k0_prep<<<641, 256, 0, stream>>>(cvt, row1, wt, inv_row);
  kLN<<<NROWS/4, 256, 0, stream>>>(cvt, resHn);
  kQKV<<<dim3(NROWS/16, 3), 256, 0, stream>>>(resHn, wt, Qw, Kw, Vw);
  kTQTK<<<dim3(NROWS/16, 2), 256, 0, stream>>>(Qw, Kw, wt, TQw, TKw);
  k2_knn<<<NRES, 256, 0, stream>>>(cvt, batch, nbr);
  k5_ligproj<<<4*LC, 128, 0, stream>>>(cvt, wt, lf, Klw, Vlw);
  k3a_logits<<<NEDGE, 256, 0, stream>>>(cvt, nbr, Qw, Kw, TQw, TKw, cT, sigT, LGw, FRw);
  k3b_att<<<NEDGE, 256, 0, stream>>>(cvt, res_S, nbr, LGw, FRw, Vw, r_ws, aVe, dXe);
  k4_agg<<<NRES, 128, 0, stream>>>(cvt, res_S, inv_row, r_ws, aVe, dXe, resHn, wt, flag,
                                   resH2, resX2, d_out);
  k6a_logits<<<NE1, 256, 0, stream>>>(cvt, row1, col1, resX2, Qw, Klw, sig1T, LG1w);
  k6b_att<<<NE1, 256, 0, stream>>>(cvt, res_S, row1, col1, LG1w, Vw, Vlw, r1w, aVrw, aVlgw);
  k7_finalH<<<NRES, 128, 0, stream>>>(inv_row, res_S, resH2, aVrw, wt, flag, d_out);
  k8_lf2<<<4*LC, 128, 0, stream>>>(col1, r1w, aVlgw, lf, wt, flag, d_out);
}